// Round 1
// baseline (3498.371 us; speedup 1.0000x reference)
//
#include <hip/hip_runtime.h>
#include <hip/hip_bf16.h>
#include <cmath>

typedef unsigned short u16;
typedef __attribute__((ext_vector_type(8))) short short8;
typedef __attribute__((ext_vector_type(4))) float f32x4;

__device__ __forceinline__ u16 f2bf(float x) {
    unsigned u = __float_as_uint(x);
    u += 0x7fffu + ((u >> 16) & 1u);
    return (u16)(u >> 16);
}

// ---------------- transpose + cast: w[K][N] f32 -> wt[N][K] bf16 ----------------
__global__ void k_transpose_cast(const float* __restrict__ in, u16* __restrict__ out,
                                 int K, int N) {
    __shared__ float tile[32][33];
    int tx = threadIdx.x, ty = threadIdx.y;
    int n0 = blockIdx.x * 32, k0 = blockIdx.y * 32;
#pragma unroll
    for (int j = 0; j < 4; ++j)
        tile[ty + j * 8][tx] = in[(size_t)(k0 + ty + j * 8) * N + n0 + tx];
    __syncthreads();
#pragma unroll
    for (int j = 0; j < 4; ++j)
        out[(size_t)(n0 + ty + j * 8) * K + k0 + tx] = f2bf(tile[tx][ty + j * 8]);
}

// ---------------- LayerNorm (fp32 in) -> bf16 out; 4 rows/block, 1 wave/row ----
__global__ __launch_bounds__(256)
void k_ln_bf16(const float* __restrict__ in, const float* __restrict__ gam,
               const float* __restrict__ bet, u16* __restrict__ out, int F) {
    int lane = threadIdx.x & 63, w = threadIdx.x >> 6;
    int row = blockIdx.x * 4 + w;
    const float* r = in + (size_t)row * F;
    float s = 0.f, s2 = 0.f;
    for (int j = lane; j < F; j += 64) { float v = r[j]; s += v; s2 += v * v; }
#pragma unroll
    for (int off = 32; off; off >>= 1) { s += __shfl_xor(s, off); s2 += __shfl_xor(s2, off); }
    float mean = s / F;
    float var  = s2 / F - mean * mean;
    float inv  = 1.f / sqrtf(var + 1e-5f);
    u16* o = out + (size_t)row * F;
    for (int j = lane; j < F; j += 64)
        o[j] = f2bf((r[j] - mean) * inv * gam[j] + bet[j]);
}

// ---------------- GEGLU: hid[M,2F] f32 -> out[M,F] bf16 (a * gelu_exact(g)) ----
__global__ __launch_bounds__(256)
void k_geglu(const float* __restrict__ hid, u16* __restrict__ out, int Mrows, int F) {
    size_t total = (size_t)Mrows * F;
    for (size_t idx = (size_t)blockIdx.x * blockDim.x + threadIdx.x; idx < total;
         idx += (size_t)gridDim.x * blockDim.x) {
        size_t r = idx / F, c = idx - r * F;
        float a = hid[r * 2 * F + c];
        float g = hid[r * 2 * F + F + c];
        float ge = 0.5f * g * (1.f + erff(g * 0.70710678118654752f));
        out[idx] = f2bf(a * ge);
    }
}

// ---------------- bf16 MFMA GEMM: C[M,N] = A[M,K] @ Bt[N,K]^T (+bias +res) -----
// 128x128 tile, 4 waves (2x2), each wave 64x64 = 4x4 frags of 16x16x32 MFMA.
__global__ __launch_bounds__(256)
void gemm_bt(const u16* __restrict__ A, const u16* __restrict__ Bt,
             const float* __restrict__ bias, const float* __restrict__ res,
             float* __restrict__ out32, u16* __restrict__ out16,
             int M, int N, int K) {
    __shared__ __align__(16) u16 As[128 * 32];
    __shared__ __align__(16) u16 Bs[128 * 32];
    const int tid = threadIdx.x;
    const int lane = tid & 63;
    const int wid = tid >> 6;
    const int wr = wid >> 1, wc = wid & 1;
    const int m0 = blockIdx.y * 128, n0 = blockIdx.x * 128;
    const int r16 = lane & 15;          // A/B fragment row/col within 16
    const int g8  = (lane >> 4) * 8;    // k-offset of this lane's 8-elem run
    const int colb = (tid & 3) * 8;     // staging: 8-elem column chunk

    const f32x4 zero4 = {0.f, 0.f, 0.f, 0.f};
    f32x4 acc[4][4];
#pragma unroll
    for (int m = 0; m < 4; ++m)
#pragma unroll
        for (int n = 0; n < 4; ++n) acc[m][n] = zero4;

    for (int k0 = 0; k0 < K; k0 += 32) {
#pragma unroll
        for (int p = 0; p < 2; ++p) {
            int row = ((p << 8) + tid) >> 2;   // 0..127
            const uint4 va = *reinterpret_cast<const uint4*>(A + (size_t)(m0 + row) * K + k0 + colb);
            *reinterpret_cast<uint4*>(&As[row * 32 + colb]) = va;
            const uint4 vb = *reinterpret_cast<const uint4*>(Bt + (size_t)(n0 + row) * K + k0 + colb);
            *reinterpret_cast<uint4*>(&Bs[row * 32 + colb]) = vb;
        }
        __syncthreads();
        short8 af[4], bfr[4];
#pragma unroll
        for (int m = 0; m < 4; ++m)
            af[m] = *reinterpret_cast<const short8*>(&As[(wr * 64 + m * 16 + r16) * 32 + g8]);
#pragma unroll
        for (int n = 0; n < 4; ++n)
            bfr[n] = *reinterpret_cast<const short8*>(&Bs[(wc * 64 + n * 16 + r16) * 32 + g8]);
#pragma unroll
        for (int m = 0; m < 4; ++m)
#pragma unroll
            for (int n = 0; n < 4; ++n)
                acc[m][n] = __builtin_amdgcn_mfma_f32_16x16x32_bf16(af[m], bfr[n], acc[m][n], 0, 0, 0);
        __syncthreads();
    }

    const int rg = (lane >> 4) * 4;     // C/D row group: row=(lane>>4)*4+j, col=lane&15
#pragma unroll
    for (int m = 0; m < 4; ++m) {
#pragma unroll
        for (int n = 0; n < 4; ++n) {
#pragma unroll
            for (int j = 0; j < 4; ++j) {
                int row = m0 + wr * 64 + m * 16 + rg + j;
                int col = n0 + wc * 64 + n * 16 + r16;
                float v = acc[m][n][j];
                if (bias) v += bias[col];
                size_t off = (size_t)row * N + col;
                if (res) v += res[off];
                if (out32) out32[off] = v;
                if (out16) out16[off] = f2bf(v);
            }
        }
    }
}

// ---------------- SDPA attention, 256 keys/batch, 8 heads, dh=64 ---------------
// 1 wave per (b,h,q). Q rows [B*NQ,512], K/V rows [B*256,512], head h at col h*64.
__global__ __launch_bounds__(256)
void k_attn256(const float* __restrict__ Q, const float* __restrict__ Kb,
               const float* __restrict__ Vb, u16* __restrict__ out, int NQ) {
    __shared__ __align__(16) float qs[4][64];
    __shared__ float ps[4][256];
    int lane = threadIdx.x & 63, w = threadIdx.x >> 6;
    int gid = blockIdx.x * 4 + w;
    int q = gid % NQ;
    int h = (gid / NQ) & 7;
    int b = gid / (NQ * 8);
    qs[w][lane] = Q[((size_t)(b * NQ + q)) * 512 + h * 64 + lane];
    __syncthreads();
    float s[4] = {0.f, 0.f, 0.f, 0.f};
    const float4* q4 = reinterpret_cast<const float4*>(qs[w]);
    const float* kbase = Kb + (size_t)b * 256 * 512 + h * 64;
#pragma unroll 4
    for (int d4 = 0; d4 < 16; ++d4) {
        float4 qv = q4[d4];
#pragma unroll
        for (int j = 0; j < 4; ++j) {
            const float4 kv = *reinterpret_cast<const float4*>(kbase + (size_t)(lane + j * 64) * 512 + d4 * 4);
            s[j] += qv.x * kv.x + qv.y * kv.y + qv.z * kv.z + qv.w * kv.w;
        }
    }
#pragma unroll
    for (int j = 0; j < 4; ++j) s[j] *= 0.125f;
    float m = fmaxf(fmaxf(s[0], s[1]), fmaxf(s[2], s[3]));
#pragma unroll
    for (int off = 32; off; off >>= 1) m = fmaxf(m, __shfl_xor(m, off));
    float e[4], sum = 0.f;
#pragma unroll
    for (int j = 0; j < 4; ++j) { e[j] = expf(s[j] - m); sum += e[j]; }
#pragma unroll
    for (int off = 32; off; off >>= 1) sum += __shfl_xor(sum, off);
    float inv = 1.f / sum;
#pragma unroll
    for (int j = 0; j < 4; ++j) ps[w][lane + j * 64] = e[j] * inv;
    __syncthreads();
    float o = 0.f;
    const float* vbase = Vb + (size_t)b * 256 * 512 + h * 64 + lane;
    for (int kk = 0; kk < 256; ++kk)
        o += ps[w][kk] * vbase[(size_t)kk * 512];
    out[((size_t)(b * NQ + q)) * 512 + h * 64 + lane] = f2bf(o);
}

// ---------------- top-32 sparse self-attention, N=2304, dh=64 ------------------
// Block = 4 queries of one (b,h). Full 2304 scores in LDS; iterative argmax x32.
__global__ __launch_bounds__(256)
void k_topk_attn(const float* __restrict__ Q, const float* __restrict__ Kb,
                 const float* __restrict__ Vb, u16* __restrict__ out) {
    __shared__ float sc[4][2304];
    __shared__ float Kt[64][65];   // transposed K tile: Kt[d][key], pad->conflict-free
    __shared__ float qs[4][64];
    __shared__ float topv[4][32];
    __shared__ int   topi[4][32];
    int tid = threadIdx.x, lane = tid & 63, w = tid >> 6;
    int bh = blockIdx.x / 576;            // 576 = 2304/4 blocks per (b,h)
    int b = bh >> 3, h = bh & 7;
    int q = (blockIdx.x % 576) * 4 + w;
    qs[w][lane] = Q[((size_t)(b * 2304 + q)) * 512 + h * 64 + lane];
    const float* kbase = Kb + (size_t)b * 2304 * 512 + h * 64;
    for (int t = 0; t < 36; ++t) {
        __syncthreads();
#pragma unroll
        for (int it = 0; it < 4; ++it) {
            int f = it * 256 + tid;
            int key = f >> 4, d = (f & 15) * 4;
            const float4 kv = *reinterpret_cast<const float4*>(kbase + (size_t)(t * 64 + key) * 512 + d);
            Kt[d][key] = kv.x; Kt[d + 1][key] = kv.y; Kt[d + 2][key] = kv.z; Kt[d + 3][key] = kv.w;
        }
        __syncthreads();
        float s = 0.f;
#pragma unroll 8
        for (int d = 0; d < 64; ++d) s += qs[w][d] * Kt[d][lane];
        sc[w][t * 64 + lane] = s * 0.125f;
    }
    __syncthreads();
    const float NEG = -3.0e38f;
    for (int it = 0; it < 32; ++it) {
        float bv = NEG; int bi = 0x7fffffff;
#pragma unroll 6
        for (int j = 0; j < 36; ++j) {
            int idx = lane + j * 64;
            float v = sc[w][idx];
            if (v > bv || (v == bv && idx < bi)) { bv = v; bi = idx; }
        }
#pragma unroll
        for (int off = 32; off; off >>= 1) {
            float ov = __shfl_xor(bv, off);
            int   oi = __shfl_xor(bi, off);
            if (ov > bv || (ov == bv && oi < bi)) { bv = ov; bi = oi; }
        }
        if (lane == 0) { topv[w][it] = bv; topi[w][it] = bi; sc[w][bi] = NEG; }
        __syncthreads();
    }
    float m = topv[w][0];                 // first argmax is the global max
    float e = (lane < 32) ? expf(topv[w][lane] - m) : 0.f;
    float sum = e;
#pragma unroll
    for (int off = 32; off; off >>= 1) sum += __shfl_xor(sum, off);
    float inv = 1.f / sum;
    if (lane < 32) topv[w][lane] = e * inv;
    __syncthreads();
    float o = 0.f;
    const float* vbase = Vb + (size_t)b * 2304 * 512 + h * 64 + lane;
#pragma unroll 8
    for (int i = 0; i < 32; ++i)
        o += topv[w][i] * vbase[(size_t)topi[w][i] * 512];
    out[((size_t)(b * 2304 + q)) * 512 + h * 64 + lane] = f2bf(o);
}

// ---------------- workspace layout (bytes; everything multiple of 256) ---------
static constexpr size_t O_WQC = 0;
static constexpr size_t O_WKC = O_WQC + 786432;
static constexpr size_t O_WVC = O_WKC + 786432;
static constexpr size_t O_WOC = O_WVC + 786432;
static constexpr size_t O_W1C = O_WOC + 786432;     // [6144,768] bf16
static constexpr size_t O_W2C = O_W1C + 9437184;    // [768,3072]
static constexpr size_t O_WQI = O_W2C + 4718592;    // [512,512]
static constexpr size_t O_WKI = O_WQI + 524288;
static constexpr size_t O_WVI = O_WKI + 524288;
static constexpr size_t O_WOI = O_WVI + 524288;
static constexpr size_t O_WQX = O_WOI + 524288;
static constexpr size_t O_WKX = O_WQX + 524288;     // [512,768]
static constexpr size_t O_WVX = O_WKX + 786432;
static constexpr size_t O_WOX = O_WVX + 786432;
static constexpr size_t O_W1I = O_WOX + 524288;     // [4096,512]
static constexpr size_t O_W2I = O_W1I + 4194304;    // [512,2048]
static constexpr size_t O_CF16 = O_W2I + 2097152;   // final ctx bf16 [512,768]
static constexpr size_t O_H    = O_CF16 + 786432;   // [4608,512] f32
static constexpr size_t O_H2   = O_H + 9437184;
static constexpr size_t O_S    = O_H2 + 9437184;    // reusable scratch zone
// ctx phase
static constexpr size_t O_CN16 = O_S;
static constexpr size_t O_QC   = O_CN16 + 786432;
static constexpr size_t O_KC   = O_QC + 1048576;
static constexpr size_t O_VC   = O_KC + 1048576;
static constexpr size_t O_AO16 = O_VC + 1048576;
static constexpr size_t O_CBUF = O_AO16 + 524288;
static constexpr size_t O_C16  = O_CBUF + 1572864;
static constexpr size_t O_FFH  = O_C16 + 786432;
static constexpr size_t O_AG16 = O_FFH + 12582912;
// img phase 1 (reuses ctx scratch)
static constexpr size_t O_XLN  = O_S;
static constexpr size_t O_QI   = O_XLN + 4718592;
static constexpr size_t O_KI   = O_QI + 9437184;
static constexpr size_t O_VI   = O_KI + 9437184;
static constexpr size_t O_TO16 = O_VI + 9437184;
// img phase 2 (reuses img1; TO16 consumed before these are written)
static constexpr size_t O_H2LN = O_S;
static constexpr size_t O_XQ   = O_H2LN + 4718592;
static constexpr size_t O_CKb  = O_XQ + 9437184;
static constexpr size_t O_CVb  = O_CKb + 1048576;
static constexpr size_t O_XO16 = O_CVb + 1048576;
// ff phase
static constexpr size_t O_H3   = O_S;
static constexpr size_t O_FFIH = O_H3 + 4718592;    // [4608,4096] f32
static constexpr size_t O_AGI  = O_FFIH + 75497472; // [4608,2048] bf16

extern "C" void kernel_launch(void* const* d_in, const int* in_sizes, int n_in,
                              void* d_out, int out_size, void* d_ws, size_t ws_size,
                              hipStream_t stream) {
    (void)in_sizes; (void)n_in; (void)out_size; (void)ws_size;
    const float* x      = (const float*)d_in[0];
    const float* ctx    = (const float*)d_in[1];
    const float* ctx_wq = (const float*)d_in[3];
    const float* ctx_wk = (const float*)d_in[4];
    const float* ctx_wv = (const float*)d_in[5];
    const float* ctx_wo = (const float*)d_in[6];
    const float* ctx_bo = (const float*)d_in[7];
    const float* cn_g   = (const float*)d_in[8];
    const float* cn_b   = (const float*)d_in[9];
    const float* im_wq  = (const float*)d_in[10];
    const float* im_wk  = (const float*)d_in[11];
    const float* im_wv  = (const float*)d_in[12];
    const float* im_wo  = (const float*)d_in[13];
    const float* im_bo  = (const float*)d_in[14];
    const float* xc_wq  = (const float*)d_in[15];
    const float* xc_wk  = (const float*)d_in[16];
    const float* xc_wv  = (const float*)d_in[17];
    const float* xc_wo  = (const float*)d_in[18];
    const float* xc_bo  = (const float*)d_in[19];
    const float* ffc_w1 = (const float*)d_in[20];
    const float* ffc_b1 = (const float*)d_in[21];
    const float* ffc_w2 = (const float*)d_in[22];
    const float* ffc_b2 = (const float*)d_in[23];
    const float* ffi_w1 = (const float*)d_in[24];
    const float* ffi_b1 = (const float*)d_in[25];
    const float* ffi_w2 = (const float*)d_in[26];
    const float* ffi_b2 = (const float*)d_in[27];
    const float* n1_g   = (const float*)d_in[28];
    const float* n1_b   = (const float*)d_in[29];
    const float* n2_g   = (const float*)d_in[30];
    const float* n2_b   = (const float*)d_in[31];
    const float* n3_g   = (const float*)d_in[32];
    const float* n3_b   = (const float*)d_in[33];
    char* ws = (char*)d_ws;
    float* out = (float*)d_out;
    auto Wp = [&](size_t off) { return (u16*)(ws + off); };
    auto Fp = [&](size_t off) { return (float*)(ws + off); };
    dim3 tb(32, 8);

    // ---- weight transpose+cast to bf16 [N,K] ----
    k_transpose_cast<<<dim3(16, 24), tb, 0, stream>>>(ctx_wq, Wp(O_WQC), 768, 512);
    k_transpose_cast<<<dim3(16, 24), tb, 0, stream>>>(ctx_wk, Wp(O_WKC), 768, 512);
    k_transpose_cast<<<dim3(16, 24), tb, 0, stream>>>(ctx_wv, Wp(O_WVC), 768, 512);
    k_transpose_cast<<<dim3(24, 16), tb, 0, stream>>>(ctx_wo, Wp(O_WOC), 512, 768);
    k_transpose_cast<<<dim3(192, 24), tb, 0, stream>>>(ffc_w1, Wp(O_W1C), 768, 6144);
    k_transpose_cast<<<dim3(24, 96), tb, 0, stream>>>(ffc_w2, Wp(O_W2C), 3072, 768);
    k_transpose_cast<<<dim3(16, 16), tb, 0, stream>>>(im_wq, Wp(O_WQI), 512, 512);
    k_transpose_cast<<<dim3(16, 16), tb, 0, stream>>>(im_wk, Wp(O_WKI), 512, 512);
    k_transpose_cast<<<dim3(16, 16), tb, 0, stream>>>(im_wv, Wp(O_WVI), 512, 512);
    k_transpose_cast<<<dim3(16, 16), tb, 0, stream>>>(im_wo, Wp(O_WOI), 512, 512);
    k_transpose_cast<<<dim3(16, 16), tb, 0, stream>>>(xc_wq, Wp(O_WQX), 512, 512);
    k_transpose_cast<<<dim3(16, 24), tb, 0, stream>>>(xc_wk, Wp(O_WKX), 768, 512);
    k_transpose_cast<<<dim3(16, 24), tb, 0, stream>>>(xc_wv, Wp(O_WVX), 768, 512);
    k_transpose_cast<<<dim3(16, 16), tb, 0, stream>>>(xc_wo, Wp(O_WOX), 512, 512);
    k_transpose_cast<<<dim3(128, 16), tb, 0, stream>>>(ffi_w1, Wp(O_W1I), 512, 4096);
    k_transpose_cast<<<dim3(16, 64), tb, 0, stream>>>(ffi_w2, Wp(O_W2I), 2048, 512);

    // ---- context path ----
    k_ln_bf16<<<128, 256, 0, stream>>>(ctx, cn_g, cn_b, Wp(O_CN16), 768);
    gemm_bt<<<dim3(4, 4), 256, 0, stream>>>(Wp(O_CN16), Wp(O_WQC), nullptr, nullptr, Fp(O_QC), nullptr, 512, 512, 768);
    gemm_bt<<<dim3(4, 4), 256, 0, stream>>>(Wp(O_CN16), Wp(O_WKC), nullptr, nullptr, Fp(O_KC), nullptr, 512, 512, 768);
    gemm_bt<<<dim3(4, 4), 256, 0, stream>>>(Wp(O_CN16), Wp(O_WVC), nullptr, nullptr, Fp(O_VC), nullptr, 512, 512, 768);
    k_attn256<<<1024, 256, 0, stream>>>(Fp(O_QC), Fp(O_KC), Fp(O_VC), Wp(O_AO16), 256);
    gemm_bt<<<dim3(6, 4), 256, 0, stream>>>(Wp(O_AO16), Wp(O_WOC), ctx_bo, ctx, Fp(O_CBUF), Wp(O_C16), 512, 768, 512);
    gemm_bt<<<dim3(48, 4), 256, 0, stream>>>(Wp(O_C16), Wp(O_W1C), ffc_b1, nullptr, Fp(O_FFH), nullptr, 512, 6144, 768);
    k_geglu<<<6144, 256, 0, stream>>>(Fp(O_FFH), Wp(O_AG16), 512, 3072);
    gemm_bt<<<dim3(6, 4), 256, 0, stream>>>(Wp(O_AG16), Wp(O_W2C), ffc_b2, Fp(O_CBUF), nullptr, Wp(O_CF16), 512, 768, 3072);

    // ---- image: top-k self-attention ----
    k_ln_bf16<<<1152, 256, 0, stream>>>(x, n1_g, n1_b, Wp(O_XLN), 512);
    gemm_bt<<<dim3(4, 36), 256, 0, stream>>>(Wp(O_XLN), Wp(O_WQI), nullptr, nullptr, Fp(O_QI), nullptr, 4608, 512, 512);
    gemm_bt<<<dim3(4, 36), 256, 0, stream>>>(Wp(O_XLN), Wp(O_WKI), nullptr, nullptr, Fp(O_KI), nullptr, 4608, 512, 512);
    gemm_bt<<<dim3(4, 36), 256, 0, stream>>>(Wp(O_XLN), Wp(O_WVI), nullptr, nullptr, Fp(O_VI), nullptr, 4608, 512, 512);
    k_topk_attn<<<9216, 256, 0, stream>>>(Fp(O_QI), Fp(O_KI), Fp(O_VI), Wp(O_TO16));
    gemm_bt<<<dim3(4, 36), 256, 0, stream>>>(Wp(O_TO16), Wp(O_WOI), im_bo, x, Fp(O_H), nullptr, 4608, 512, 512);

    // ---- image -> context cross-attention ----
    k_ln_bf16<<<1152, 256, 0, stream>>>(Fp(O_H), n2_g, n2_b, Wp(O_H2LN), 512);
    gemm_bt<<<dim3(4, 36), 256, 0, stream>>>(Wp(O_H2LN), Wp(O_WQX), nullptr, nullptr, Fp(O_XQ), nullptr, 4608, 512, 512);
    gemm_bt<<<dim3(4, 4), 256, 0, stream>>>(Wp(O_CF16), Wp(O_WKX), nullptr, nullptr, Fp(O_CKb), nullptr, 512, 512, 768);
    gemm_bt<<<dim3(4, 4), 256, 0, stream>>>(Wp(O_CF16), Wp(O_WVX), nullptr, nullptr, Fp(O_CVb), nullptr, 512, 512, 768);
    k_attn256<<<9216, 256, 0, stream>>>(Fp(O_XQ), Fp(O_CKb), Fp(O_CVb), Wp(O_XO16), 2304);
    gemm_bt<<<dim3(4, 36), 256, 0, stream>>>(Wp(O_XO16), Wp(O_WOX), xc_bo, Fp(O_H), Fp(O_H2), nullptr, 4608, 512, 512);

    // ---- image GEGLU FF ----
    k_ln_bf16<<<1152, 256, 0, stream>>>(Fp(O_H2), n3_g, n3_b, Wp(O_H3), 512);
    gemm_bt<<<dim3(32, 36), 256, 0, stream>>>(Wp(O_H3), Wp(O_W1I), ffi_b1, nullptr, Fp(O_FFIH), nullptr, 4608, 4096, 512);
    k_geglu<<<8192, 256, 0, stream>>>(Fp(O_FFIH), Wp(O_AGI), 4608, 2048);
    gemm_bt<<<dim3(4, 36), 256, 0, stream>>>(Wp(O_AGI), Wp(O_W2I), ffi_b2, Fp(O_H2), out, nullptr, 4608, 512, 2048);
}

// Round 2
// 1270.722 us; speedup vs baseline: 2.7531x; 2.7531x over previous
//
#include <hip/hip_runtime.h>
#include <hip/hip_bf16.h>
#include <hip/hip_fp16.h>
#include <cmath>

typedef unsigned short u16;
typedef unsigned long long ull;
typedef __attribute__((ext_vector_type(8))) short short8;
typedef __attribute__((ext_vector_type(4))) float f32x4;

__device__ __forceinline__ u16 f2bf(float x) {
    unsigned u = __float_as_uint(x);
    u += 0x7fffu + ((u >> 16) & 1u);
    return (u16)(u >> 16);
}

// sortable-u16 key <-> f16 bits (order-preserving map)
__device__ __forceinline__ unsigned h2key(unsigned hb) {
    return (hb & 0x8000u) ? (hb ^ 0xFFFFu) : (hb | 0x8000u);
}
__device__ __forceinline__ float key2f(unsigned k) {
    unsigned hb = (k & 0x8000u) ? (k ^ 0x8000u) : (k ^ 0xFFFFu);
    return __half2float(__ushort_as_half((unsigned short)hb));
}

// ---------------- transpose + cast: w[K][N] f32 -> wt[N][K] bf16 ----------------
__global__ void k_transpose_cast(const float* __restrict__ in, u16* __restrict__ out,
                                 int K, int N) {
    __shared__ float tile[32][33];
    int tx = threadIdx.x, ty = threadIdx.y;
    int n0 = blockIdx.x * 32, k0 = blockIdx.y * 32;
#pragma unroll
    for (int j = 0; j < 4; ++j)
        tile[ty + j * 8][tx] = in[(size_t)(k0 + ty + j * 8) * N + n0 + tx];
    __syncthreads();
#pragma unroll
    for (int j = 0; j < 4; ++j)
        out[(size_t)(n0 + ty + j * 8) * K + k0 + tx] = f2bf(tile[tx][ty + j * 8]);
}

// ---------------- LayerNorm (fp32 in) -> bf16 out; 4 rows/block, 1 wave/row ----
__global__ __launch_bounds__(256)
void k_ln_bf16(const float* __restrict__ in, const float* __restrict__ gam,
               const float* __restrict__ bet, u16* __restrict__ out, int F) {
    int lane = threadIdx.x & 63, w = threadIdx.x >> 6;
    int row = blockIdx.x * 4 + w;
    const float* r = in + (size_t)row * F;
    float s = 0.f, s2 = 0.f;
    for (int j = lane; j < F; j += 64) { float v = r[j]; s += v; s2 += v * v; }
#pragma unroll
    for (int off = 32; off; off >>= 1) { s += __shfl_xor(s, off); s2 += __shfl_xor(s2, off); }
    float mean = s / F;
    float var  = s2 / F - mean * mean;
    float inv  = 1.f / sqrtf(var + 1e-5f);
    u16* o = out + (size_t)row * F;
    for (int j = lane; j < F; j += 64)
        o[j] = f2bf((r[j] - mean) * inv * gam[j] + bet[j]);
}

// ---------------- GEGLU: hid[M,2F] f32 -> out[M,F] bf16 (a * gelu_exact(g)) ----
__global__ __launch_bounds__(256)
void k_geglu(const float* __restrict__ hid, u16* __restrict__ out, int Mrows, int F) {
    size_t total = (size_t)Mrows * F;
    for (size_t idx = (size_t)blockIdx.x * blockDim.x + threadIdx.x; idx < total;
         idx += (size_t)gridDim.x * blockDim.x) {
        size_t r = idx / F, c = idx - r * F;
        float a = hid[r * 2 * F + c];
        float g = hid[r * 2 * F + F + c];
        float ge = 0.5f * g * (1.f + erff(g * 0.70710678118654752f));
        out[idx] = f2bf(a * ge);
    }
}

// ---------------- bf16 MFMA GEMM: C[M,N] = A[M,K] @ Bt[N,K]^T (+bias +res) -----
__global__ __launch_bounds__(256)
void gemm_bt(const u16* __restrict__ A, const u16* __restrict__ Bt,
             const float* __restrict__ bias, const float* __restrict__ res,
             float* __restrict__ out32, u16* __restrict__ out16,
             int M, int N, int K) {
    __shared__ __align__(16) u16 As[128 * 32];
    __shared__ __align__(16) u16 Bs[128 * 32];
    const int tid = threadIdx.x;
    const int lane = tid & 63;
    const int wid = tid >> 6;
    const int wr = wid >> 1, wc = wid & 1;
    const int m0 = blockIdx.y * 128, n0 = blockIdx.x * 128;
    const int r16 = lane & 15;
    const int g8  = (lane >> 4) * 8;
    const int colb = (tid & 3) * 8;

    const f32x4 zero4 = {0.f, 0.f, 0.f, 0.f};
    f32x4 acc[4][4];
#pragma unroll
    for (int m = 0; m < 4; ++m)
#pragma unroll
        for (int n = 0; n < 4; ++n) acc[m][n] = zero4;

    for (int k0 = 0; k0 < K; k0 += 32) {
#pragma unroll
        for (int p = 0; p < 2; ++p) {
            int row = ((p << 8) + tid) >> 2;
            const uint4 va = *reinterpret_cast<const uint4*>(A + (size_t)(m0 + row) * K + k0 + colb);
            *reinterpret_cast<uint4*>(&As[row * 32 + colb]) = va;
            const uint4 vb = *reinterpret_cast<const uint4*>(Bt + (size_t)(n0 + row) * K + k0 + colb);
            *reinterpret_cast<uint4*>(&Bs[row * 32 + colb]) = vb;
        }
        __syncthreads();
        short8 af[4], bfr[4];
#pragma unroll
        for (int m = 0; m < 4; ++m)
            af[m] = *reinterpret_cast<const short8*>(&As[(wr * 64 + m * 16 + r16) * 32 + g8]);
#pragma unroll
        for (int n = 0; n < 4; ++n)
            bfr[n] = *reinterpret_cast<const short8*>(&Bs[(wc * 64 + n * 16 + r16) * 32 + g8]);
#pragma unroll
        for (int m = 0; m < 4; ++m)
#pragma unroll
            for (int n = 0; n < 4; ++n)
                acc[m][n] = __builtin_amdgcn_mfma_f32_16x16x32_bf16(af[m], bfr[n], acc[m][n], 0, 0, 0);
        __syncthreads();
    }

    const int rg = (lane >> 4) * 4;
#pragma unroll
    for (int m = 0; m < 4; ++m) {
#pragma unroll
        for (int n = 0; n < 4; ++n) {
#pragma unroll
            for (int j = 0; j < 4; ++j) {
                int row = m0 + wr * 64 + m * 16 + rg + j;
                int col = n0 + wc * 64 + n * 16 + r16;
                float v = acc[m][n][j];
                if (bias) v += bias[col];
                size_t off = (size_t)row * N + col;
                if (res) v += res[off];
                if (out32) out32[off] = v;
                if (out16) out16[off] = f2bf(v);
            }
        }
    }
}

// ---------------- SDPA attention, 256 keys/batch, 8 heads, dh=64 ---------------
__global__ __launch_bounds__(256)
void k_attn256(const float* __restrict__ Q, const float* __restrict__ Kb,
               const float* __restrict__ Vb, u16* __restrict__ out, int NQ) {
    __shared__ __align__(16) float qs[4][64];
    __shared__ float ps[4][256];
    int lane = threadIdx.x & 63, w = threadIdx.x >> 6;
    int gid = blockIdx.x * 4 + w;
    int q = gid % NQ;
    int h = (gid / NQ) & 7;
    int b = gid / (NQ * 8);
    qs[w][lane] = Q[((size_t)(b * NQ + q)) * 512 + h * 64 + lane];
    __syncthreads();
    float s[4] = {0.f, 0.f, 0.f, 0.f};
    const float4* q4 = reinterpret_cast<const float4*>(qs[w]);
    const float* kbase = Kb + (size_t)b * 256 * 512 + h * 64;
#pragma unroll 4
    for (int d4 = 0; d4 < 16; ++d4) {
        float4 qv = q4[d4];
#pragma unroll
        for (int j = 0; j < 4; ++j) {
            const float4 kv = *reinterpret_cast<const float4*>(kbase + (size_t)(lane + j * 64) * 512 + d4 * 4);
            s[j] += qv.x * kv.x + qv.y * kv.y + qv.z * kv.z + qv.w * kv.w;
        }
    }
#pragma unroll
    for (int j = 0; j < 4; ++j) s[j] *= 0.125f;
    float m = fmaxf(fmaxf(s[0], s[1]), fmaxf(s[2], s[3]));
#pragma unroll
    for (int off = 32; off; off >>= 1) m = fmaxf(m, __shfl_xor(m, off));
    float e[4], sum = 0.f;
#pragma unroll
    for (int j = 0; j < 4; ++j) { e[j] = expf(s[j] - m); sum += e[j]; }
#pragma unroll
    for (int off = 32; off; off >>= 1) sum += __shfl_xor(sum, off);
    float inv = 1.f / sum;
#pragma unroll
    for (int j = 0; j < 4; ++j) ps[w][lane + j * 64] = e[j] * inv;
    __syncthreads();
    float o = 0.f;
    const float* vbase = Vb + (size_t)b * 256 * 512 + h * 64 + lane;
    for (int kk = 0; kk < 256; ++kk)
        o += ps[w][kk] * vbase[(size_t)kk * 512];
    out[((size_t)(b * NQ + q)) * 512 + h * 64 + lane] = f2bf(o);
}

// ---------------- top-32 sparse self-attention, N=2304, dh=64 ------------------
// Block = 8 queries of one (b,h), 4 waves. Scores via MFMA (bf16 Q,K direct from
// global), stored f16 in LDS. Selection = per-wave 16-bit radix-select over
// register-resident sortable keys (no LDS, no barriers), then ballot extraction.
__global__ __launch_bounds__(256)
void k_topk_attn(const u16* __restrict__ Qb, const u16* __restrict__ Kb,
                 const float* __restrict__ Vb, u16* __restrict__ out) {
    __shared__ u16   sc[8][2312];    // f16 scores, pad 8 -> conflict-free scatter
    __shared__ int   ilist[8][32];
    __shared__ float wlist[8][32];
    const int tid = threadIdx.x, lane = tid & 63, w = tid >> 6;
    const int bh = blockIdx.x / 288;
    const int b = bh >> 3, h = bh & 7;
    const int q0 = (blockIdx.x % 288) * 8;
    const int r16 = lane & 15;
    const int g8  = (lane >> 4) * 8;
    const int rq  = (lane >> 4) * 4;   // C row group base (query index)

    // A fragments: Q rows q0..q0+15 (rows >= 8 are don't-care padding; reads may
    // touch neighboring ws regions but C rows of pad queries are discarded).
    const size_t qrow = ((size_t)(b * 2304 + q0 + r16)) * 512 + h * 64;
    const short8 af0 = *reinterpret_cast<const short8*>(Qb + qrow + g8);
    const short8 af1 = *reinterpret_cast<const short8*>(Qb + qrow + 32 + g8);

    const u16* kb = Kb + (size_t)b * 2304 * 512 + h * 64;
    const f32x4 zero4 = {0.f, 0.f, 0.f, 0.f};
    for (int t = 0; t < 36; ++t) {
        const size_t krow = ((size_t)(t * 64 + w * 16 + r16)) * 512;
        const short8 bf0 = *reinterpret_cast<const short8*>(kb + krow + g8);
        const short8 bf1 = *reinterpret_cast<const short8*>(kb + krow + 32 + g8);
        f32x4 acc = zero4;
        acc = __builtin_amdgcn_mfma_f32_16x16x32_bf16(af0, bf0, acc, 0, 0, 0);
        acc = __builtin_amdgcn_mfma_f32_16x16x32_bf16(af1, bf1, acc, 0, 0, 0);
        const int col = t * 64 + w * 16 + r16;
        if (rq < 8) {
#pragma unroll
            for (int j = 0; j < 4; ++j)
                sc[rq + j][col] = __half_as_ushort(__float2half(acc[j] * 0.125f));
        }
    }
    __syncthreads();

    const ull ltm = (1ull << lane) - 1ull;
    for (int round = 0; round < 2; ++round) {
        const int q = w * 2 + round;
        unsigned key[36];
        unsigned kmax = 0;
#pragma unroll
        for (int j = 0; j < 36; ++j) {
            unsigned hb = sc[q][lane + j * 64];
            key[j] = h2key(hb);
            kmax = key[j] > kmax ? key[j] : kmax;
        }
#pragma unroll
        for (int off = 32; off; off >>= 1) {
            unsigned o = (unsigned)__shfl_xor((int)kmax, off);
            kmax = o > kmax ? o : kmax;
        }
        // exact 32nd-largest key via MSB-first binary search
        unsigned thr = 0;
        for (int bit = 15; bit >= 0; --bit) {
            unsigned cand = thr | (1u << bit);
            int c = 0;
#pragma unroll
            for (int j = 0; j < 36; ++j) c += (key[j] >= cand) ? 1 : 0;
#pragma unroll
            for (int off = 32; off; off >>= 1) c += __shfl_xor(c, off);
            if (c >= 32) { thr = cand; if (c == 32) break; }
        }
        // strict pass: all keys > thr (set membership; order irrelevant)
        int tot = 0;
#pragma unroll
        for (int j = 0; j < 36; ++j) {
            bool p = key[j] > thr;
            ull m = __ballot(p);
            if (p) {
                int pos = tot + (int)__popcll(m & ltm);
                ilist[q][pos] = j * 64 + lane;
                wlist[q][pos] = key2f(key[j]);
            }
            tot += (int)__popcll(m);
        }
        // tie pass: keys == thr, taken in ascending global index order
        const int r = 32 - tot;
        const float tv = key2f(thr);
        int t2 = 0;
#pragma unroll
        for (int j = 0; j < 36; ++j) {
            bool p = (key[j] == thr) && (t2 < 32);
            ull m = __ballot(p);
            if (p) {
                int pos = t2 + (int)__popcll(m & ltm);
                if (pos < r) {
                    ilist[q][tot + pos] = j * 64 + lane;
                    wlist[q][tot + pos] = tv;
                }
            }
            t2 += (int)__popcll(m);
        }
        // softmax over the 32 selected (max = kmax by construction)
        const float mf = key2f(kmax);
        float e = 0.f;
        if (lane < 32) e = expf(wlist[q][lane] - mf);
        float sum = e;
#pragma unroll
        for (int off = 32; off; off >>= 1) sum += __shfl_xor(sum, off);
        if (lane < 32) wlist[q][lane] = e / sum;
        // PV gather: o[d=lane] = sum_i w[i] * V[idx[i]][d]
        float o = 0.f;
        const float* vb = Vb + (size_t)b * 2304 * 512 + h * 64 + lane;
#pragma unroll 8
        for (int i = 0; i < 32; ++i)
            o += wlist[q][i] * vb[(size_t)ilist[q][i] * 512];
        out[((size_t)(b * 2304 + q0 + q)) * 512 + h * 64 + lane] = f2bf(o);
    }
}

// ---------------- workspace layout (bytes) ---------------
static constexpr size_t O_WQC = 0;
static constexpr size_t O_WKC = O_WQC + 786432;
static constexpr size_t O_WVC = O_WKC + 786432;
static constexpr size_t O_WOC = O_WVC + 786432;
static constexpr size_t O_W1C = O_WOC + 786432;
static constexpr size_t O_W2C = O_W1C + 9437184;
static constexpr size_t O_WQI = O_W2C + 4718592;
static constexpr size_t O_WKI = O_WQI + 524288;
static constexpr size_t O_WVI = O_WKI + 524288;
static constexpr size_t O_WOI = O_WVI + 524288;
static constexpr size_t O_WQX = O_WOI + 524288;
static constexpr size_t O_WKX = O_WQX + 524288;
static constexpr size_t O_WVX = O_WKX + 786432;
static constexpr size_t O_WOX = O_WVX + 786432;
static constexpr size_t O_W1I = O_WOX + 524288;
static constexpr size_t O_W2I = O_W1I + 4194304;
static constexpr size_t O_CF16 = O_W2I + 2097152;
static constexpr size_t O_H    = O_CF16 + 786432;
static constexpr size_t O_H2   = O_H + 9437184;
static constexpr size_t O_S    = O_H2 + 9437184;
// ctx phase
static constexpr size_t O_CN16 = O_S;
static constexpr size_t O_QC   = O_CN16 + 786432;
static constexpr size_t O_KC   = O_QC + 1048576;
static constexpr size_t O_VC   = O_KC + 1048576;
static constexpr size_t O_AO16 = O_VC + 1048576;
static constexpr size_t O_CBUF = O_AO16 + 524288;
static constexpr size_t O_C16  = O_CBUF + 1572864;
static constexpr size_t O_FFH  = O_C16 + 786432;
static constexpr size_t O_AG16 = O_FFH + 12582912;
// img phase 1
static constexpr size_t O_XLN  = O_S;
static constexpr size_t O_QI   = O_XLN + 4718592;   // bf16 [4608,512] (region oversized)
static constexpr size_t O_KI   = O_QI + 9437184;    // bf16 [4608,512]
static constexpr size_t O_VI   = O_KI + 9437184;    // f32  [4608,512]
static constexpr size_t O_TO16 = O_VI + 9437184;
// img phase 2
static constexpr size_t O_H2LN = O_S;
static constexpr size_t O_XQ   = O_H2LN + 4718592;
static constexpr size_t O_CKb  = O_XQ + 9437184;
static constexpr size_t O_CVb  = O_CKb + 1048576;
static constexpr size_t O_XO16 = O_CVb + 1048576;
// ff phase
static constexpr size_t O_H3   = O_S;
static constexpr size_t O_FFIH = O_H3 + 4718592;
static constexpr size_t O_AGI  = O_FFIH + 75497472;

extern "C" void kernel_launch(void* const* d_in, const int* in_sizes, int n_in,
                              void* d_out, int out_size, void* d_ws, size_t ws_size,
                              hipStream_t stream) {
    (void)in_sizes; (void)n_in; (void)out_size; (void)ws_size;
    const float* x      = (const float*)d_in[0];
    const float* ctx    = (const float*)d_in[1];
    const float* ctx_wq = (const float*)d_in[3];
    const float* ctx_wk = (const float*)d_in[4];
    const float* ctx_wv = (const float*)d_in[5];
    const float* ctx_wo = (const float*)d_in[6];
    const float* ctx_bo = (const float*)d_in[7];
    const float* cn_g   = (const float*)d_in[8];
    const float* cn_b   = (const float*)d_in[9];
    const float* im_wq  = (const float*)d_in[10];
    const float* im_wk  = (const float*)d_in[11];
    const float* im_wv  = (const float*)d_in[12];
    const float* im_wo  = (const float*)d_in[13];
    const float* im_bo  = (const float*)d_in[14];
    const float* xc_wq  = (const float*)d_in[15];
    const float* xc_wk  = (const float*)d_in[16];
    const float* xc_wv  = (const float*)d_in[17];
    const float* xc_wo  = (const float*)d_in[18];
    const float* xc_bo  = (const float*)d_in[19];
    const float* ffc_w1 = (const float*)d_in[20];
    const float* ffc_b1 = (const float*)d_in[21];
    const float* ffc_w2 = (const float*)d_in[22];
    const float* ffc_b2 = (const float*)d_in[23];
    const float* ffi_w1 = (const float*)d_in[24];
    const float* ffi_b1 = (const float*)d_in[25];
    const float* ffi_w2 = (const float*)d_in[26];
    const float* ffi_b2 = (const float*)d_in[27];
    const float* n1_g   = (const float*)d_in[28];
    const float* n1_b   = (const float*)d_in[29];
    const float* n2_g   = (const float*)d_in[30];
    const float* n2_b   = (const float*)d_in[31];
    const float* n3_g   = (const float*)d_in[32];
    const float* n3_b   = (const float*)d_in[33];
    char* ws = (char*)d_ws;
    float* out = (float*)d_out;
    auto Wp = [&](size_t off) { return (u16*)(ws + off); };
    auto Fp = [&](size_t off) { return (float*)(ws + off); };
    dim3 tb(32, 8);

    // ---- weight transpose+cast to bf16 [N,K] ----
    k_transpose_cast<<<dim3(16, 24), tb, 0, stream>>>(ctx_wq, Wp(O_WQC), 768, 512);
    k_transpose_cast<<<dim3(16, 24), tb, 0, stream>>>(ctx_wk, Wp(O_WKC), 768, 512);
    k_transpose_cast<<<dim3(16, 24), tb, 0, stream>>>(ctx_wv, Wp(O_WVC), 768, 512);
    k_transpose_cast<<<dim3(24, 16), tb, 0, stream>>>(ctx_wo, Wp(O_WOC), 512, 768);
    k_transpose_cast<<<dim3(192, 24), tb, 0, stream>>>(ffc_w1, Wp(O_W1C), 768, 6144);
    k_transpose_cast<<<dim3(24, 96), tb, 0, stream>>>(ffc_w2, Wp(O_W2C), 3072, 768);
    k_transpose_cast<<<dim3(16, 16), tb, 0, stream>>>(im_wq, Wp(O_WQI), 512, 512);
    k_transpose_cast<<<dim3(16, 16), tb, 0, stream>>>(im_wk, Wp(O_WKI), 512, 512);
    k_transpose_cast<<<dim3(16, 16), tb, 0, stream>>>(im_wv, Wp(O_WVI), 512, 512);
    k_transpose_cast<<<dim3(16, 16), tb, 0, stream>>>(im_wo, Wp(O_WOI), 512, 512);
    k_transpose_cast<<<dim3(16, 16), tb, 0, stream>>>(xc_wq, Wp(O_WQX), 512, 512);
    k_transpose_cast<<<dim3(16, 24), tb, 0, stream>>>(xc_wk, Wp(O_WKX), 768, 512);
    k_transpose_cast<<<dim3(16, 24), tb, 0, stream>>>(xc_wv, Wp(O_WVX), 768, 512);
    k_transpose_cast<<<dim3(16, 16), tb, 0, stream>>>(xc_wo, Wp(O_WOX), 512, 512);
    k_transpose_cast<<<dim3(128, 16), tb, 0, stream>>>(ffi_w1, Wp(O_W1I), 512, 4096);
    k_transpose_cast<<<dim3(16, 64), tb, 0, stream>>>(ffi_w2, Wp(O_W2I), 2048, 512);

    // ---- context path ----
    k_ln_bf16<<<128, 256, 0, stream>>>(ctx, cn_g, cn_b, Wp(O_CN16), 768);
    gemm_bt<<<dim3(4, 4), 256, 0, stream>>>(Wp(O_CN16), Wp(O_WQC), nullptr, nullptr, Fp(O_QC), nullptr, 512, 512, 768);
    gemm_bt<<<dim3(4, 4), 256, 0, stream>>>(Wp(O_CN16), Wp(O_WKC), nullptr, nullptr, Fp(O_KC), nullptr, 512, 512, 768);
    gemm_bt<<<dim3(4, 4), 256, 0, stream>>>(Wp(O_CN16), Wp(O_WVC), nullptr, nullptr, Fp(O_VC), nullptr, 512, 512, 768);
    k_attn256<<<1024, 256, 0, stream>>>(Fp(O_QC), Fp(O_KC), Fp(O_VC), Wp(O_AO16), 256);
    gemm_bt<<<dim3(6, 4), 256, 0, stream>>>(Wp(O_AO16), Wp(O_WOC), ctx_bo, ctx, Fp(O_CBUF), Wp(O_C16), 512, 768, 512);
    gemm_bt<<<dim3(48, 4), 256, 0, stream>>>(Wp(O_C16), Wp(O_W1C), ffc_b1, nullptr, Fp(O_FFH), nullptr, 512, 6144, 768);
    k_geglu<<<6144, 256, 0, stream>>>(Fp(O_FFH), Wp(O_AG16), 512, 3072);
    gemm_bt<<<dim3(6, 4), 256, 0, stream>>>(Wp(O_AG16), Wp(O_W2C), ffc_b2, Fp(O_CBUF), nullptr, Wp(O_CF16), 512, 768, 3072);

    // ---- image: top-k self-attention (Q,K in bf16 for MFMA scores; V f32) ----
    k_ln_bf16<<<1152, 256, 0, stream>>>(x, n1_g, n1_b, Wp(O_XLN), 512);
    gemm_bt<<<dim3(4, 36), 256, 0, stream>>>(Wp(O_XLN), Wp(O_WQI), nullptr, nullptr, nullptr, Wp(O_QI), 4608, 512, 512);
    gemm_bt<<<dim3(4, 36), 256, 0, stream>>>(Wp(O_XLN), Wp(O_WKI), nullptr, nullptr, nullptr, Wp(O_KI), 4608, 512, 512);
    gemm_bt<<<dim3(4, 36), 256, 0, stream>>>(Wp(O_XLN), Wp(O_WVI), nullptr, nullptr, Fp(O_VI), nullptr, 4608, 512, 512);
    k_topk_attn<<<4608, 256, 0, stream>>>(Wp(O_QI), Wp(O_KI), Fp(O_VI), Wp(O_TO16));
    gemm_bt<<<dim3(4, 36), 256, 0, stream>>>(Wp(O_TO16), Wp(O_WOI), im_bo, x, Fp(O_H), nullptr, 4608, 512, 512);

    // ---- image -> context cross-attention ----
    k_ln_bf16<<<1152, 256, 0, stream>>>(Fp(O_H), n2_g, n2_b, Wp(O_H2LN), 512);
    gemm_bt<<<dim3(4, 36), 256, 0, stream>>>(Wp(O_H2LN), Wp(O_WQX), nullptr, nullptr, Fp(O_XQ), nullptr, 4608, 512, 512);
    gemm_bt<<<dim3(4, 4), 256, 0, stream>>>(Wp(O_CF16), Wp(O_WKX), nullptr, nullptr, Fp(O_CKb), nullptr, 512, 512, 768);
    gemm_bt<<<dim3(4, 4), 256, 0, stream>>>(Wp(O_CF16), Wp(O_WVX), nullptr, nullptr, Fp(O_CVb), nullptr, 512, 512, 768);
    k_attn256<<<9216, 256, 0, stream>>>(Fp(O_XQ), Fp(O_CKb), Fp(O_CVb), Wp(O_XO16), 2304);
    gemm_bt<<<dim3(4, 36), 256, 0, stream>>>(Wp(O_XO16), Wp(O_WOX), xc_bo, Fp(O_H), Fp(O_H2), nullptr, 4608, 512, 512);

    // ---- image GEGLU FF ----
    k_ln_bf16<<<1152, 256, 0, stream>>>(Fp(O_H2), n3_g, n3_b, Wp(O_H3), 512);
    gemm_bt<<<dim3(32, 36), 256, 0, stream>>>(Wp(O_H3), Wp(O_W1I), ffi_b1, nullptr, Fp(O_FFIH), nullptr, 4608, 4096, 512);
    k_geglu<<<8192, 256, 0, stream>>>(Fp(O_FFIH), Wp(O_AGI), 4608, 2048);
    gemm_bt<<<dim3(4, 36), 256, 0, stream>>>(Wp(O_AGI), Wp(O_W2I), ffi_b2, Fp(O_H2), out, nullptr, 4608, 512, 2048);
}

// Round 3
// 891.714 us; speedup vs baseline: 3.9232x; 1.4250x over previous
//
#include <hip/hip_runtime.h>
#include <hip/hip_bf16.h>
#include <hip/hip_fp16.h>
#include <cmath>

typedef unsigned short u16;
typedef unsigned long long ull;
typedef __attribute__((ext_vector_type(8))) short short8;
typedef __attribute__((ext_vector_type(4))) float f32x4;
typedef __attribute__((ext_vector_type(4))) unsigned short u16x4;

__device__ __forceinline__ u16 f2bf(float x) {
    unsigned u = __float_as_uint(x);
    u += 0x7fffu + ((u >> 16) & 1u);
    return (u16)(u >> 16);
}
__device__ __forceinline__ float bf2f(u16 b) {
    return __uint_as_float(((unsigned)b) << 16);
}

// sortable-u16 key <-> f16 bits (order-preserving map)
__device__ __forceinline__ unsigned h2key(unsigned hb) {
    return (hb & 0x8000u) ? (hb ^ 0xFFFFu) : (hb | 0x8000u);
}
__device__ __forceinline__ float key2f(unsigned k) {
    unsigned hb = (k & 0x8000u) ? (k ^ 0x8000u) : (k ^ 0xFFFFu);
    return __half2float(__ushort_as_half((unsigned short)hb));
}

// ---------------- batched transpose+cast: w[K][N] f32 -> wt[N][K] bf16 --------
struct TBatch {
    const float* src[16];
    u16* dst[16];
    int K[16];
    int N[16];
    int start[17];
};

__global__ void k_transpose_cast_batch(TBatch tb) {
    __shared__ float tile[32][33];
    int t = blockIdx.x;
    int m = 0;
    while (t >= tb.start[m + 1]) ++m;
    int rel = t - tb.start[m];
    const int K = tb.K[m], N = tb.N[m];
    const int ntx = N >> 5;
    const int n0 = (rel % ntx) * 32, k0 = (rel / ntx) * 32;
    const float* __restrict__ in = tb.src[m];
    u16* __restrict__ out = tb.dst[m];
    int tx = threadIdx.x, ty = threadIdx.y;
#pragma unroll
    for (int j = 0; j < 4; ++j)
        tile[ty + j * 8][tx] = in[(size_t)(k0 + ty + j * 8) * N + n0 + tx];
    __syncthreads();
#pragma unroll
    for (int j = 0; j < 4; ++j)
        out[(size_t)(n0 + ty + j * 8) * K + k0 + tx] = f2bf(tile[tx][ty + j * 8]);
}

// ---------------- V transpose: V f32 [2*256][512] -> VT bf16 [2][512][256] ----
__global__ void k_vtrans(const float* __restrict__ in, u16* __restrict__ out) {
    __shared__ float tile[32][33];
    int tx = threadIdx.x, ty = threadIdx.y;
    int d0 = blockIdx.x * 32, k0 = blockIdx.y * 32, b = blockIdx.z;
#pragma unroll
    for (int j = 0; j < 4; ++j)
        tile[ty + j * 8][tx] = in[(size_t)(b * 256 + k0 + ty + j * 8) * 512 + d0 + tx];
    __syncthreads();
#pragma unroll
    for (int j = 0; j < 4; ++j)
        out[(size_t)(b * 512 + d0 + ty + j * 8) * 256 + k0 + tx] = f2bf(tile[tx][ty + j * 8]);
}

// ---------------- LayerNorm (fp32 in) -> bf16 out; 4 rows/block, 1 wave/row ----
__global__ __launch_bounds__(256)
void k_ln_bf16(const float* __restrict__ in, const float* __restrict__ gam,
               const float* __restrict__ bet, u16* __restrict__ out, int F) {
    int lane = threadIdx.x & 63, w = threadIdx.x >> 6;
    int row = blockIdx.x * 4 + w;
    const float* r = in + (size_t)row * F;
    float s = 0.f, s2 = 0.f;
    for (int j = lane; j < F; j += 64) { float v = r[j]; s += v; s2 += v * v; }
#pragma unroll
    for (int off = 32; off; off >>= 1) { s += __shfl_xor(s, off); s2 += __shfl_xor(s2, off); }
    float mean = s / F;
    float var  = s2 / F - mean * mean;
    float inv  = 1.f / sqrtf(var + 1e-5f);
    u16* o = out + (size_t)row * F;
    for (int j = lane; j < F; j += 64)
        o[j] = f2bf((r[j] - mean) * inv * gam[j] + bet[j]);
}

// ---------------- GEGLU: hid[M,2F] bf16 -> out[M,F] bf16 (a * gelu_exact(g)) --
__global__ __launch_bounds__(256)
void k_geglu(const u16* __restrict__ hid, u16* __restrict__ out, int Mrows, int F) {
    const int F4 = F >> 2;
    size_t total = (size_t)Mrows * F4;
    for (size_t i4 = (size_t)blockIdx.x * blockDim.x + threadIdx.x; i4 < total;
         i4 += (size_t)gridDim.x * blockDim.x) {
        size_t r = i4 / F4, c4 = (i4 - r * F4) * 4;
        u16x4 a4 = *reinterpret_cast<const u16x4*>(hid + r * 2 * F + c4);
        u16x4 g4 = *reinterpret_cast<const u16x4*>(hid + r * 2 * F + F + c4);
        u16x4 o4;
#pragma unroll
        for (int j = 0; j < 4; ++j) {
            float a = bf2f(a4[j]), g = bf2f(g4[j]);
            float ge = 0.5f * g * (1.f + erff(g * 0.70710678118654752f));
            o4[j] = f2bf(a * ge);
        }
        *reinterpret_cast<u16x4*>(out + r * F + c4) = o4;
    }
}

// ---------------- bf16 MFMA GEMM: C[M,N] = A[M,K] @ Bt[N,K]^T (+bias +res) -----
__global__ __launch_bounds__(256)
void gemm_bt(const u16* __restrict__ A, const u16* __restrict__ Bt,
             const float* __restrict__ bias, const float* __restrict__ res,
             float* __restrict__ out32, u16* __restrict__ out16,
             int M, int N, int K) {
    __shared__ __align__(16) u16 As[128 * 32];
    __shared__ __align__(16) u16 Bs[128 * 32];
    const int tid = threadIdx.x;
    const int lane = tid & 63;
    const int wid = tid >> 6;
    const int wr = wid >> 1, wc = wid & 1;
    const int m0 = blockIdx.y * 128, n0 = blockIdx.x * 128;
    const int r16 = lane & 15;
    const int g8  = (lane >> 4) * 8;
    const int colb = (tid & 3) * 8;

    const f32x4 zero4 = {0.f, 0.f, 0.f, 0.f};
    f32x4 acc[4][4];
#pragma unroll
    for (int m = 0; m < 4; ++m)
#pragma unroll
        for (int n = 0; n < 4; ++n) acc[m][n] = zero4;

    for (int k0 = 0; k0 < K; k0 += 32) {
#pragma unroll
        for (int p = 0; p < 2; ++p) {
            int row = ((p << 8) + tid) >> 2;
            const uint4 va = *reinterpret_cast<const uint4*>(A + (size_t)(m0 + row) * K + k0 + colb);
            *reinterpret_cast<uint4*>(&As[row * 32 + colb]) = va;
            const uint4 vb = *reinterpret_cast<const uint4*>(Bt + (size_t)(n0 + row) * K + k0 + colb);
            *reinterpret_cast<uint4*>(&Bs[row * 32 + colb]) = vb;
        }
        __syncthreads();
        short8 af[4], bfr[4];
#pragma unroll
        for (int m = 0; m < 4; ++m)
            af[m] = *reinterpret_cast<const short8*>(&As[(wr * 64 + m * 16 + r16) * 32 + g8]);
#pragma unroll
        for (int n = 0; n < 4; ++n)
            bfr[n] = *reinterpret_cast<const short8*>(&Bs[(wc * 64 + n * 16 + r16) * 32 + g8]);
#pragma unroll
        for (int m = 0; m < 4; ++m)
#pragma unroll
            for (int n = 0; n < 4; ++n)
                acc[m][n] = __builtin_amdgcn_mfma_f32_16x16x32_bf16(af[m], bfr[n], acc[m][n], 0, 0, 0);
        __syncthreads();
    }

    const int rg = (lane >> 4) * 4;
#pragma unroll
    for (int m = 0; m < 4; ++m) {
#pragma unroll
        for (int n = 0; n < 4; ++n) {
#pragma unroll
            for (int j = 0; j < 4; ++j) {
                int row = m0 + wr * 64 + m * 16 + rg + j;
                int col = n0 + wc * 64 + n * 16 + r16;
                float v = acc[m][n][j];
                if (bias) v += bias[col];
                size_t off = (size_t)row * N + col;
                if (res) v += res[off];
                if (out32) out32[off] = v;
                if (out16) out16[off] = f2bf(v);
            }
        }
    }
}

// ---------------- MFMA SDPA attention, 256 keys, 8 heads, dh=64 ----------------
// Block = 16 queries of one (b,h), 4 waves. Scores + PV both via MFMA.
// Qb,Kb bf16 [rows][512]; VT bf16 [B][512][256] (VT[b][d][k] = V[b*256+k][d]).
__global__ __launch_bounds__(256)
void k_attn_mfma(const u16* __restrict__ Qb, const u16* __restrict__ Kb,
                 const u16* __restrict__ VT, u16* __restrict__ out, int NQ) {
    __shared__ float sc[16][268];
    __shared__ u16   pb[16][268];
    const int tid = threadIdx.x, lane = tid & 63, w = tid >> 6;
    const int nqb = NQ >> 4;
    const int q0 = (blockIdx.x % nqb) << 4;
    const int h = (blockIdx.x / nqb) & 7;
    const int b = blockIdx.x / (nqb * 8);
    const int r16 = lane & 15, g8 = (lane >> 4) * 8, rq = (lane >> 4) * 4;

    const size_t qrow = ((size_t)(b * NQ + q0 + r16)) * 512 + h * 64;
    const short8 af0 = *reinterpret_cast<const short8*>(Qb + qrow + g8);
    const short8 af1 = *reinterpret_cast<const short8*>(Qb + qrow + 32 + g8);
    const u16* kb = Kb + (size_t)b * 256 * 512 + h * 64;
    const f32x4 zero4 = {0.f, 0.f, 0.f, 0.f};
#pragma unroll
    for (int t = 0; t < 4; ++t) {
        const size_t krow = (size_t)(t * 64 + w * 16 + r16) * 512;
        const short8 bf0 = *reinterpret_cast<const short8*>(kb + krow + g8);
        const short8 bf1 = *reinterpret_cast<const short8*>(kb + krow + 32 + g8);
        f32x4 acc = __builtin_amdgcn_mfma_f32_16x16x32_bf16(af0, bf0, zero4, 0, 0, 0);
        acc = __builtin_amdgcn_mfma_f32_16x16x32_bf16(af1, bf1, acc, 0, 0, 0);
        const int col = t * 64 + w * 16 + r16;
#pragma unroll
        for (int j = 0; j < 4; ++j) sc[rq + j][col] = acc[j] * 0.125f;
    }
    __syncthreads();
    // softmax: wave w owns queries w*4..w*4+3; 256 scores = 4/lane
#pragma unroll
    for (int qi = 0; qi < 4; ++qi) {
        const int q = w * 4 + qi;
        float4 v = *reinterpret_cast<const float4*>(&sc[q][lane * 4]);
        float m = fmaxf(fmaxf(v.x, v.y), fmaxf(v.z, v.w));
#pragma unroll
        for (int off = 32; off; off >>= 1) m = fmaxf(m, __shfl_xor(m, off));
        float e0 = expf(v.x - m), e1 = expf(v.y - m), e2 = expf(v.z - m), e3 = expf(v.w - m);
        float sum = e0 + e1 + e2 + e3;
#pragma unroll
        for (int off = 32; off; off >>= 1) sum += __shfl_xor(sum, off);
        float inv = 1.f / sum;
        u16x4 p4;
        p4[0] = f2bf(e0 * inv); p4[1] = f2bf(e1 * inv);
        p4[2] = f2bf(e2 * inv); p4[3] = f2bf(e3 * inv);
        *reinterpret_cast<u16x4*>(&pb[q][lane * 4]) = p4;
    }
    __syncthreads();
    // PV: C[16q x 16d per wave] = P[16x256] x V[256x64]
    f32x4 o = zero4;
    const u16* vt = VT + ((size_t)(b * 512 + h * 64 + w * 16 + r16)) * 256;
#pragma unroll
    for (int kk = 0; kk < 8; ++kk) {
        const short8 pa = *reinterpret_cast<const short8*>(&pb[r16][kk * 32 + g8]);
        const short8 vv = *reinterpret_cast<const short8*>(vt + kk * 32 + g8);
        o = __builtin_amdgcn_mfma_f32_16x16x32_bf16(pa, vv, o, 0, 0, 0);
    }
#pragma unroll
    for (int j = 0; j < 4; ++j)
        out[((size_t)(b * NQ + q0 + rq + j)) * 512 + h * 64 + w * 16 + r16] = f2bf(o[j]);
}

// ---------------- top-32 sparse self-attention, N=2304, dh=64 ------------------
__global__ __launch_bounds__(256)
void k_topk_attn(const u16* __restrict__ Qb, const u16* __restrict__ Kb,
                 const float* __restrict__ Vb, u16* __restrict__ out) {
    __shared__ u16   sc[8][2312];
    __shared__ int   ilist[8][32];
    __shared__ float wlist[8][32];
    const int tid = threadIdx.x, lane = tid & 63, w = tid >> 6;
    const int bh = blockIdx.x / 288;
    const int b = bh >> 3, h = bh & 7;
    const int q0 = (blockIdx.x % 288) * 8;
    const int r16 = lane & 15;
    const int g8  = (lane >> 4) * 8;
    const int rq  = (lane >> 4) * 4;

    const size_t qrow = ((size_t)(b * 2304 + q0 + r16)) * 512 + h * 64;
    const short8 af0 = *reinterpret_cast<const short8*>(Qb + qrow + g8);
    const short8 af1 = *reinterpret_cast<const short8*>(Qb + qrow + 32 + g8);

    const u16* kb = Kb + (size_t)b * 2304 * 512 + h * 64;
    const f32x4 zero4 = {0.f, 0.f, 0.f, 0.f};
    for (int t = 0; t < 36; ++t) {
        const size_t krow = ((size_t)(t * 64 + w * 16 + r16)) * 512;
        const short8 bf0 = *reinterpret_cast<const short8*>(kb + krow + g8);
        const short8 bf1 = *reinterpret_cast<const short8*>(kb + krow + 32 + g8);
        f32x4 acc = __builtin_amdgcn_mfma_f32_16x16x32_bf16(af0, bf0, zero4, 0, 0, 0);
        acc = __builtin_amdgcn_mfma_f32_16x16x32_bf16(af1, bf1, acc, 0, 0, 0);
        const int col = t * 64 + w * 16 + r16;
        if (rq < 8) {
#pragma unroll
            for (int j = 0; j < 4; ++j)
                sc[rq + j][col] = __half_as_ushort(__float2half(acc[j] * 0.125f));
        }
    }
    __syncthreads();

    const ull ltm = (1ull << lane) - 1ull;
    for (int round = 0; round < 2; ++round) {
        const int q = w * 2 + round;
        unsigned key[36];
        unsigned kmax = 0;
#pragma unroll
        for (int j = 0; j < 36; ++j) {
            unsigned hb = sc[q][lane + j * 64];
            key[j] = h2key(hb);
            kmax = key[j] > kmax ? key[j] : kmax;
        }
#pragma unroll
        for (int off = 32; off; off >>= 1) {
            unsigned o = (unsigned)__shfl_xor((int)kmax, off);
            kmax = o > kmax ? o : kmax;
        }
        unsigned thr = 0;
        for (int bit = 15; bit >= 0; --bit) {
            unsigned cand = thr | (1u << bit);
            int c = 0;
#pragma unroll
            for (int j = 0; j < 36; ++j) c += (key[j] >= cand) ? 1 : 0;
#pragma unroll
            for (int off = 32; off; off >>= 1) c += __shfl_xor(c, off);
            if (c >= 32) { thr = cand; if (c == 32) break; }
        }
        int tot = 0;
#pragma unroll
        for (int j = 0; j < 36; ++j) {
            bool p = key[j] > thr;
            ull m = __ballot(p);
            if (p) {
                int pos = tot + (int)__popcll(m & ltm);
                ilist[q][pos] = j * 64 + lane;
                wlist[q][pos] = key2f(key[j]);
            }
            tot += (int)__popcll(m);
        }
        const int r = 32 - tot;
        const float tv = key2f(thr);
        int t2 = 0;
#pragma unroll
        for (int j = 0; j < 36; ++j) {
            bool p = (key[j] == thr) && (t2 < 32);
            ull m = __ballot(p);
            if (p) {
                int pos = t2 + (int)__popcll(m & ltm);
                if (pos < r) {
                    ilist[q][tot + pos] = j * 64 + lane;
                    wlist[q][tot + pos] = tv;
                }
            }
            t2 += (int)__popcll(m);
        }
        const float mf = key2f(kmax);
        float e = 0.f;
        if (lane < 32) e = expf(wlist[q][lane] - mf);
        float sum = e;
#pragma unroll
        for (int off = 32; off; off >>= 1) sum += __shfl_xor(sum, off);
        if (lane < 32) wlist[q][lane] = e / sum;
        float o = 0.f;
        const float* vb = Vb + (size_t)b * 2304 * 512 + h * 64 + lane;
#pragma unroll 8
        for (int i = 0; i < 32; ++i)
            o += wlist[q][i] * vb[(size_t)ilist[q][i] * 512];
        out[((size_t)(b * 2304 + q0 + q)) * 512 + h * 64 + lane] = f2bf(o);
    }
}

// ---------------- workspace layout (bytes) ---------------
static constexpr size_t O_WQC = 0;
static constexpr size_t O_WKC = O_WQC + 786432;
static constexpr size_t O_WVC = O_WKC + 786432;
static constexpr size_t O_WVCp = O_WVC + 786432;
static constexpr size_t O_WOC = O_WVCp;
static constexpr size_t O_W1C = O_WOC + 786432;
static constexpr size_t O_W2C = O_W1C + 9437184;
static constexpr size_t O_WQI = O_W2C + 4718592;
static constexpr size_t O_WKI = O_WQI + 524288;
static constexpr size_t O_WVI = O_WKI + 524288;
static constexpr size_t O_WOI = O_WVI + 524288;
static constexpr size_t O_WQX = O_WOI + 524288;
static constexpr size_t O_WKX = O_WQX + 524288;
static constexpr size_t O_WVX = O_WKX + 786432;
static constexpr size_t O_WOX = O_WVX + 786432;
static constexpr size_t O_W1I = O_WOX + 524288;
static constexpr size_t O_W2I = O_W1I + 4194304;
static constexpr size_t O_CF16 = O_W2I + 2097152;
static constexpr size_t O_H    = O_CF16 + 786432;
static constexpr size_t O_H2   = O_H + 9437184;
static constexpr size_t O_S    = O_H2 + 9437184;
// ctx phase
static constexpr size_t O_CN16 = O_S;
static constexpr size_t O_QC   = O_CN16 + 786432;
static constexpr size_t O_KC   = O_QC + 1048576;
static constexpr size_t O_VC   = O_KC + 1048576;
static constexpr size_t O_AO16 = O_VC + 1048576;
static constexpr size_t O_CBUF = O_AO16 + 524288;
static constexpr size_t O_C16  = O_CBUF + 1572864;
static constexpr size_t O_FFH  = O_C16 + 786432;
static constexpr size_t O_AG16 = O_FFH + 12582912;
static constexpr size_t O_VTC  = O_AG16 + 3145728;   // bf16 [2][512][256]
// img phase 1
static constexpr size_t O_XLN  = O_S;
static constexpr size_t O_QI   = O_XLN + 4718592;
static constexpr size_t O_KI   = O_QI + 9437184;
static constexpr size_t O_VI   = O_KI + 9437184;
static constexpr size_t O_TO16 = O_VI + 9437184;
// img phase 2
static constexpr size_t O_H2LN = O_S;
static constexpr size_t O_XQ   = O_H2LN + 4718592;
static constexpr size_t O_CKb  = O_XQ + 9437184;
static constexpr size_t O_CVb  = O_CKb + 1048576;
static constexpr size_t O_XO16 = O_CVb + 1048576;
static constexpr size_t O_VTX  = O_XO16 + 4718592;   // bf16 [2][512][256]
// ff phase
static constexpr size_t O_H3   = O_S;
static constexpr size_t O_FFIH = O_H3 + 4718592;     // bf16 now (region oversized)
static constexpr size_t O_AGI  = O_FFIH + 75497472;

extern "C" void kernel_launch(void* const* d_in, const int* in_sizes, int n_in,
                              void* d_out, int out_size, void* d_ws, size_t ws_size,
                              hipStream_t stream) {
    (void)in_sizes; (void)n_in; (void)out_size; (void)ws_size;
    const float* x      = (const float*)d_in[0];
    const float* ctx    = (const float*)d_in[1];
    const float* ctx_wq = (const float*)d_in[3];
    const float* ctx_wk = (const float*)d_in[4];
    const float* ctx_wv = (const float*)d_in[5];
    const float* ctx_wo = (const float*)d_in[6];
    const float* ctx_bo = (const float*)d_in[7];
    const float* cn_g   = (const float*)d_in[8];
    const float* cn_b   = (const float*)d_in[9];
    const float* im_wq  = (const float*)d_in[10];
    const float* im_wk  = (const float*)d_in[11];
    const float* im_wv  = (const float*)d_in[12];
    const float* im_wo  = (const float*)d_in[13];
    const float* im_bo  = (const float*)d_in[14];
    const float* xc_wq  = (const float*)d_in[15];
    const float* xc_wk  = (const float*)d_in[16];
    const float* xc_wv  = (const float*)d_in[17];
    const float* xc_wo  = (const float*)d_in[18];
    const float* xc_bo  = (const float*)d_in[19];
    const float* ffc_w1 = (const float*)d_in[20];
    const float* ffc_b1 = (const float*)d_in[21];
    const float* ffc_w2 = (const float*)d_in[22];
    const float* ffc_b2 = (const float*)d_in[23];
    const float* ffi_w1 = (const float*)d_in[24];
    const float* ffi_b1 = (const float*)d_in[25];
    const float* ffi_w2 = (const float*)d_in[26];
    const float* ffi_b2 = (const float*)d_in[27];
    const float* n1_g   = (const float*)d_in[28];
    const float* n1_b   = (const float*)d_in[29];
    const float* n2_g   = (const float*)d_in[30];
    const float* n2_b   = (const float*)d_in[31];
    const float* n3_g   = (const float*)d_in[32];
    const float* n3_b   = (const float*)d_in[33];
    char* ws = (char*)d_ws;
    float* out = (float*)d_out;
    auto Wp = [&](size_t off) { return (u16*)(ws + off); };
    auto Fp = [&](size_t off) { return (float*)(ws + off); };
    dim3 tb(32, 8);

    // ---- one batched weight transpose+cast ----
    TBatch tbat;
    const float* srcs[16] = {ctx_wq, ctx_wk, ctx_wv, ctx_wo, ffc_w1, ffc_w2,
                             im_wq, im_wk, im_wv, im_wo, xc_wq, xc_wk, xc_wv,
                             xc_wo, ffi_w1, ffi_w2};
    const size_t dsts[16] = {O_WQC, O_WKC, O_WVC, O_WOC, O_W1C, O_W2C,
                             O_WQI, O_WKI, O_WVI, O_WOI, O_WQX, O_WKX, O_WVX,
                             O_WOX, O_W1I, O_W2I};
    const int Ks[16] = {768, 768, 768, 512, 768, 3072, 512, 512, 512, 512,
                        512, 768, 768, 512, 512, 2048};
    const int Ns[16] = {512, 512, 512, 768, 6144, 768, 512, 512, 512, 512,
                        512, 512, 512, 512, 4096, 512};
    int acc = 0;
    for (int i = 0; i < 16; ++i) {
        tbat.src[i] = srcs[i];
        tbat.dst[i] = Wp(dsts[i]);
        tbat.K[i] = Ks[i];
        tbat.N[i] = Ns[i];
        tbat.start[i] = acc;
        acc += (Ns[i] >> 5) * (Ks[i] >> 5);
    }
    tbat.start[16] = acc;
    k_transpose_cast_batch<<<acc, tb, 0, stream>>>(tbat);

    // ---- context path ----
    k_ln_bf16<<<128, 256, 0, stream>>>(ctx, cn_g, cn_b, Wp(O_CN16), 768);
    gemm_bt<<<dim3(4, 4), 256, 0, stream>>>(Wp(O_CN16), Wp(O_WQC), nullptr, nullptr, nullptr, Wp(O_QC), 512, 512, 768);
    gemm_bt<<<dim3(4, 4), 256, 0, stream>>>(Wp(O_CN16), Wp(O_WKC), nullptr, nullptr, nullptr, Wp(O_KC), 512, 512, 768);
    gemm_bt<<<dim3(4, 4), 256, 0, stream>>>(Wp(O_CN16), Wp(O_WVC), nullptr, nullptr, Fp(O_VC), nullptr, 512, 512, 768);
    k_vtrans<<<dim3(16, 8, 2), tb, 0, stream>>>(Fp(O_VC), Wp(O_VTC));
    k_attn_mfma<<<256, 256, 0, stream>>>(Wp(O_QC), Wp(O_KC), Wp(O_VTC), Wp(O_AO16), 256);
    gemm_bt<<<dim3(6, 4), 256, 0, stream>>>(Wp(O_AO16), Wp(O_WOC), ctx_bo, ctx, Fp(O_CBUF), Wp(O_C16), 512, 768, 512);
    gemm_bt<<<dim3(48, 4), 256, 0, stream>>>(Wp(O_C16), Wp(O_W1C), ffc_b1, nullptr, nullptr, Wp(O_FFH), 512, 6144, 768);
    k_geglu<<<1536, 256, 0, stream>>>(Wp(O_FFH), Wp(O_AG16), 512, 3072);
    gemm_bt<<<dim3(6, 4), 256, 0, stream>>>(Wp(O_AG16), Wp(O_W2C), ffc_b2, Fp(O_CBUF), nullptr, Wp(O_CF16), 512, 768, 3072);

    // ---- image: top-k self-attention ----
    k_ln_bf16<<<1152, 256, 0, stream>>>(x, n1_g, n1_b, Wp(O_XLN), 512);
    gemm_bt<<<dim3(4, 36), 256, 0, stream>>>(Wp(O_XLN), Wp(O_WQI), nullptr, nullptr, nullptr, Wp(O_QI), 4608, 512, 512);
    gemm_bt<<<dim3(4, 36), 256, 0, stream>>>(Wp(O_XLN), Wp(O_WKI), nullptr, nullptr, nullptr, Wp(O_KI), 4608, 512, 512);
    gemm_bt<<<dim3(4, 36), 256, 0, stream>>>(Wp(O_XLN), Wp(O_WVI), nullptr, nullptr, Fp(O_VI), nullptr, 4608, 512, 512);
    k_topk_attn<<<4608, 256, 0, stream>>>(Wp(O_QI), Wp(O_KI), Fp(O_VI), Wp(O_TO16));
    gemm_bt<<<dim3(4, 36), 256, 0, stream>>>(Wp(O_TO16), Wp(O_WOI), im_bo, x, Fp(O_H), nullptr, 4608, 512, 512);

    // ---- image -> context cross-attention ----
    k_ln_bf16<<<1152, 256, 0, stream>>>(Fp(O_H), n2_g, n2_b, Wp(O_H2LN), 512);
    gemm_bt<<<dim3(4, 36), 256, 0, stream>>>(Wp(O_H2LN), Wp(O_WQX), nullptr, nullptr, nullptr, Wp(O_XQ), 4608, 512, 512);
    gemm_bt<<<dim3(4, 4), 256, 0, stream>>>(Wp(O_CF16), Wp(O_WKX), nullptr, nullptr, nullptr, Wp(O_CKb), 512, 512, 768);
    gemm_bt<<<dim3(4, 4), 256, 0, stream>>>(Wp(O_CF16), Wp(O_WVX), nullptr, nullptr, Fp(O_CVb), nullptr, 512, 512, 768);
    k_vtrans<<<dim3(16, 8, 2), tb, 0, stream>>>(Fp(O_CVb), Wp(O_VTX));
    k_attn_mfma<<<2304, 256, 0, stream>>>(Wp(O_XQ), Wp(O_CKb), Wp(O_VTX), Wp(O_XO16), 2304);
    gemm_bt<<<dim3(4, 36), 256, 0, stream>>>(Wp(O_XO16), Wp(O_WOX), xc_bo, Fp(O_H), Fp(O_H2), nullptr, 4608, 512, 512);

    // ---- image GEGLU FF ----
    k_ln_bf16<<<1152, 256, 0, stream>>>(Fp(O_H2), n3_g, n3_b, Wp(O_H3), 512);
    gemm_bt<<<dim3(32, 36), 256, 0, stream>>>(Wp(O_H3), Wp(O_W1I), ffi_b1, nullptr, nullptr, Wp(O_FFIH), 4608, 4096, 512);
    k_geglu<<<4096, 256, 0, stream>>>(Wp(O_FFIH), Wp(O_AGI), 4608, 2048);
    gemm_bt<<<dim3(4, 36), 256, 0, stream>>>(Wp(O_AGI), Wp(O_W2I), ffi_b2, Fp(O_H2), out, nullptr, 4608, 512, 2048);
}

// Round 4
// 786.373 us; speedup vs baseline: 4.4487x; 1.1340x over previous
//
#include <hip/hip_runtime.h>
#include <hip/hip_bf16.h>
#include <hip/hip_fp16.h>
#include <cmath>

typedef unsigned short u16;
typedef unsigned long long ull;
typedef __attribute__((ext_vector_type(8))) short short8;
typedef __attribute__((ext_vector_type(4))) float f32x4;
typedef __attribute__((ext_vector_type(4))) unsigned short u16x4;

__device__ __forceinline__ u16 f2bf(float x) {
    unsigned u = __float_as_uint(x);
    u += 0x7fffu + ((u >> 16) & 1u);
    return (u16)(u >> 16);
}
__device__ __forceinline__ float bf2f(u16 b) {
    return __uint_as_float(((unsigned)b) << 16);
}

// sortable-u16 key <-> f16 bits (order-preserving map)
__device__ __forceinline__ unsigned h2key(unsigned hb) {
    return (hb & 0x8000u) ? (hb ^ 0xFFFFu) : (hb | 0x8000u);
}
__device__ __forceinline__ float key2f(unsigned k) {
    unsigned hb = (k & 0x8000u) ? (k ^ 0x8000u) : (k ^ 0xFFFFu);
    return __half2float(__ushort_as_half((unsigned short)hb));
}

// ---------------- batched transpose+cast: w[K][N] f32 -> wt[N][K] bf16 --------
struct TBatch {
    const float* src[16];
    u16* dst[16];
    int K[16];
    int N[16];
    int start[17];
};

__global__ void k_transpose_cast_batch(TBatch tb) {
    __shared__ float tile[32][33];
    int t = blockIdx.x;
    int m = 0;
    while (t >= tb.start[m + 1]) ++m;
    int rel = t - tb.start[m];
    const int K = tb.K[m], N = tb.N[m];
    const int ntx = N >> 5;
    const int n0 = (rel % ntx) * 32, k0 = (rel / ntx) * 32;
    const float* __restrict__ in = tb.src[m];
    u16* __restrict__ out = tb.dst[m];
    int tx = threadIdx.x, ty = threadIdx.y;
#pragma unroll
    for (int j = 0; j < 4; ++j)
        tile[ty + j * 8][tx] = in[(size_t)(k0 + ty + j * 8) * N + n0 + tx];
    __syncthreads();
#pragma unroll
    for (int j = 0; j < 4; ++j)
        out[(size_t)(n0 + ty + j * 8) * K + k0 + tx] = f2bf(tile[tx][ty + j * 8]);
}

// -------- V transpose (bf16 in): in[b*256+k][stride] col coloff+d -> out[b][512][256]
__global__ void k_vtrans16(const u16* __restrict__ in, int stride, int coloff,
                           u16* __restrict__ out) {
    __shared__ int tile[32][33];
    int tx = threadIdx.x, ty = threadIdx.y;
    int d0 = blockIdx.x * 32, k0 = blockIdx.y * 32, b = blockIdx.z;
#pragma unroll
    for (int j = 0; j < 4; ++j)
        tile[ty + j * 8][tx] = in[(size_t)(b * 256 + k0 + ty + j * 8) * stride + coloff + d0 + tx];
    __syncthreads();
#pragma unroll
    for (int j = 0; j < 4; ++j)
        out[(size_t)(b * 512 + d0 + ty + j * 8) * 256 + k0 + tx] = (u16)tile[tx][ty + j * 8];
}

// ---------------- LayerNorm (fp32 in) -> bf16 out; 4 rows/block, 1 wave/row ----
__global__ __launch_bounds__(256)
void k_ln_bf16(const float* __restrict__ in, const float* __restrict__ gam,
               const float* __restrict__ bet, u16* __restrict__ out, int F) {
    int lane = threadIdx.x & 63, w = threadIdx.x >> 6;
    int row = blockIdx.x * 4 + w;
    const float* r = in + (size_t)row * F;
    float s = 0.f, s2 = 0.f;
    for (int j = lane; j < F; j += 64) { float v = r[j]; s += v; s2 += v * v; }
#pragma unroll
    for (int off = 32; off; off >>= 1) { s += __shfl_xor(s, off); s2 += __shfl_xor(s2, off); }
    float mean = s / F;
    float var  = s2 / F - mean * mean;
    float inv  = 1.f / sqrtf(var + 1e-5f);
    u16* o = out + (size_t)row * F;
    for (int j = lane; j < F; j += 64)
        o[j] = f2bf((r[j] - mean) * inv * gam[j] + bet[j]);
}

// ---------------- GEGLU: hid[M,2F] bf16 -> out[M,F] bf16 (a * gelu_exact(g)) --
__global__ __launch_bounds__(256)
void k_geglu(const u16* __restrict__ hid, u16* __restrict__ out, int Mrows, int F) {
    const int F4 = F >> 2;
    size_t total = (size_t)Mrows * F4;
    for (size_t i4 = (size_t)blockIdx.x * blockDim.x + threadIdx.x; i4 < total;
         i4 += (size_t)gridDim.x * blockDim.x) {
        size_t r = i4 / F4, c4 = (i4 - r * F4) * 4;
        u16x4 a4 = *reinterpret_cast<const u16x4*>(hid + r * 2 * F + c4);
        u16x4 g4 = *reinterpret_cast<const u16x4*>(hid + r * 2 * F + F + c4);
        u16x4 o4;
#pragma unroll
        for (int j = 0; j < 4; ++j) {
            float a = bf2f(a4[j]), g = bf2f(g4[j]);
            float ge = 0.5f * g * (1.f + erff(g * 0.70710678118654752f));
            o4[j] = f2bf(a * ge);
        }
        *reinterpret_cast<u16x4*>(out + r * F + c4) = o4;
    }
}

// ---------------- bf16 MFMA GEMM: C[M,N] = A[M,K] @ Bt[N,K]^T (+bias +res) -----
__global__ __launch_bounds__(256)
void gemm_bt(const u16* __restrict__ A, const u16* __restrict__ Bt,
             const float* __restrict__ bias, const float* __restrict__ res,
             float* __restrict__ out32, u16* __restrict__ out16,
             int M, int N, int K) {
    __shared__ __align__(16) u16 As[128 * 32];
    __shared__ __align__(16) u16 Bs[128 * 32];
    const int tid = threadIdx.x;
    const int lane = tid & 63;
    const int wid = tid >> 6;
    const int wr = wid >> 1, wc = wid & 1;
    const int m0 = blockIdx.y * 128, n0 = blockIdx.x * 128;
    const int r16 = lane & 15;
    const int g8  = (lane >> 4) * 8;
    const int colb = (tid & 3) * 8;

    const f32x4 zero4 = {0.f, 0.f, 0.f, 0.f};
    f32x4 acc[4][4];
#pragma unroll
    for (int m = 0; m < 4; ++m)
#pragma unroll
        for (int n = 0; n < 4; ++n) acc[m][n] = zero4;

    for (int k0 = 0; k0 < K; k0 += 32) {
#pragma unroll
        for (int p = 0; p < 2; ++p) {
            int row = ((p << 8) + tid) >> 2;
            const uint4 va = *reinterpret_cast<const uint4*>(A + (size_t)(m0 + row) * K + k0 + colb);
            *reinterpret_cast<uint4*>(&As[row * 32 + colb]) = va;
            const uint4 vb = *reinterpret_cast<const uint4*>(Bt + (size_t)(n0 + row) * K + k0 + colb);
            *reinterpret_cast<uint4*>(&Bs[row * 32 + colb]) = vb;
        }
        __syncthreads();
        short8 af[4], bfr[4];
#pragma unroll
        for (int m = 0; m < 4; ++m)
            af[m] = *reinterpret_cast<const short8*>(&As[(wr * 64 + m * 16 + r16) * 32 + g8]);
#pragma unroll
        for (int n = 0; n < 4; ++n)
            bfr[n] = *reinterpret_cast<const short8*>(&Bs[(wc * 64 + n * 16 + r16) * 32 + g8]);
#pragma unroll
        for (int m = 0; m < 4; ++m)
#pragma unroll
            for (int n = 0; n < 4; ++n)
                acc[m][n] = __builtin_amdgcn_mfma_f32_16x16x32_bf16(af[m], bfr[n], acc[m][n], 0, 0, 0);
        __syncthreads();
    }

    const int rg = (lane >> 4) * 4;
#pragma unroll
    for (int m = 0; m < 4; ++m) {
#pragma unroll
        for (int n = 0; n < 4; ++n) {
#pragma unroll
            for (int j = 0; j < 4; ++j) {
                int row = m0 + wr * 64 + m * 16 + rg + j;
                int col = n0 + wc * 64 + n * 16 + r16;
                float v = acc[m][n][j];
                if (bias) v += bias[col];
                size_t off = (size_t)row * N + col;
                if (res) v += res[off];
                if (out32) out32[off] = v;
                if (out16) out16[off] = f2bf(v);
            }
        }
    }
}

// ---------------- MFMA SDPA attention, 256 keys, 8 heads, dh=64 ----------------
// Block = 16 queries of one (b,h), 4 waves. Scores + PV both via MFMA.
// Qb stride sq, Kb stride sk (bf16); VT bf16 [B][512][256]; out stride 512.
__global__ __launch_bounds__(256)
void k_attn_mfma(const u16* __restrict__ Qb, int sq, const u16* __restrict__ Kb,
                 int sk, const u16* __restrict__ VT, u16* __restrict__ out, int NQ) {
    __shared__ float sc[16][268];
    __shared__ u16   pb[16][268];
    const int tid = threadIdx.x, lane = tid & 63, w = tid >> 6;
    const int nqb = NQ >> 4;
    const int q0 = (blockIdx.x % nqb) << 4;
    const int h = (blockIdx.x / nqb) & 7;
    const int b = blockIdx.x / (nqb * 8);
    const int r16 = lane & 15, g8 = (lane >> 4) * 8, rq = (lane >> 4) * 4;

    const size_t qrow = ((size_t)(b * NQ + q0 + r16)) * sq + h * 64;
    const short8 af0 = *reinterpret_cast<const short8*>(Qb + qrow + g8);
    const short8 af1 = *reinterpret_cast<const short8*>(Qb + qrow + 32 + g8);
    const u16* kb = Kb + (size_t)b * 256 * sk + h * 64;
    const f32x4 zero4 = {0.f, 0.f, 0.f, 0.f};
#pragma unroll
    for (int t = 0; t < 4; ++t) {
        const size_t krow = (size_t)(t * 64 + w * 16 + r16) * sk;
        const short8 bf0 = *reinterpret_cast<const short8*>(kb + krow + g8);
        const short8 bf1 = *reinterpret_cast<const short8*>(kb + krow + 32 + g8);
        f32x4 acc = __builtin_amdgcn_mfma_f32_16x16x32_bf16(af0, bf0, zero4, 0, 0, 0);
        acc = __builtin_amdgcn_mfma_f32_16x16x32_bf16(af1, bf1, acc, 0, 0, 0);
        const int col = t * 64 + w * 16 + r16;
#pragma unroll
        for (int j = 0; j < 4; ++j) sc[rq + j][col] = acc[j] * 0.125f;
    }
    __syncthreads();
#pragma unroll
    for (int qi = 0; qi < 4; ++qi) {
        const int q = w * 4 + qi;
        float4 v = *reinterpret_cast<const float4*>(&sc[q][lane * 4]);
        float m = fmaxf(fmaxf(v.x, v.y), fmaxf(v.z, v.w));
#pragma unroll
        for (int off = 32; off; off >>= 1) m = fmaxf(m, __shfl_xor(m, off));
        float e0 = expf(v.x - m), e1 = expf(v.y - m), e2 = expf(v.z - m), e3 = expf(v.w - m);
        float sum = e0 + e1 + e2 + e3;
#pragma unroll
        for (int off = 32; off; off >>= 1) sum += __shfl_xor(sum, off);
        float inv = 1.f / sum;
        u16x4 p4;
        p4[0] = f2bf(e0 * inv); p4[1] = f2bf(e1 * inv);
        p4[2] = f2bf(e2 * inv); p4[3] = f2bf(e3 * inv);
        *reinterpret_cast<u16x4*>(&pb[q][lane * 4]) = p4;
    }
    __syncthreads();
    f32x4 o = zero4;
    const u16* vt = VT + ((size_t)(b * 512 + h * 64 + w * 16 + r16)) * 256;
#pragma unroll
    for (int kk = 0; kk < 8; ++kk) {
        const short8 pa = *reinterpret_cast<const short8*>(&pb[r16][kk * 32 + g8]);
        const short8 vv = *reinterpret_cast<const short8*>(vt + kk * 32 + g8);
        o = __builtin_amdgcn_mfma_f32_16x16x32_bf16(pa, vv, o, 0, 0, 0);
    }
#pragma unroll
    for (int j = 0; j < 4; ++j)
        out[((size_t)(b * NQ + q0 + rq + j)) * 512 + h * 64 + w * 16 + r16] = f2bf(o[j]);
}

// ---------------- top-32 sparse self-attention, N=2304, dh=64 ------------------
// Q,K,V packed bf16 rows of stride 1536 (Qb=+0, Kb=+512, Vb=+1024 col offset).
__global__ __launch_bounds__(256)
void k_topk_attn(const u16* __restrict__ Qb, const u16* __restrict__ Kb,
                 const u16* __restrict__ Vb, u16* __restrict__ out) {
    __shared__ u16   sc[8][2312];
    __shared__ int   ilist[8][32];
    __shared__ float wlist[8][32];
    const int tid = threadIdx.x, lane = tid & 63, w = tid >> 6;
    const int bh = blockIdx.x / 288;
    const int b = bh >> 3, h = bh & 7;
    const int q0 = (blockIdx.x % 288) * 8;
    const int r16 = lane & 15;
    const int g8  = (lane >> 4) * 8;
    const int rq  = (lane >> 4) * 4;

    const size_t qrow = ((size_t)(b * 2304 + q0 + r16)) * 1536 + h * 64;
    const short8 af0 = *reinterpret_cast<const short8*>(Qb + qrow + g8);
    const short8 af1 = *reinterpret_cast<const short8*>(Qb + qrow + 32 + g8);

    const u16* kb = Kb + (size_t)b * 2304 * 1536 + h * 64;
    const f32x4 zero4 = {0.f, 0.f, 0.f, 0.f};
    // score phase with one-iteration load prefetch
    size_t kr = (size_t)(w * 16 + r16) * 1536;
    short8 c0 = *reinterpret_cast<const short8*>(kb + kr + g8);
    short8 c1 = *reinterpret_cast<const short8*>(kb + kr + 32 + g8);
    for (int t = 0; t < 36; ++t) {
        const int tn = (t < 35) ? t + 1 : t;
        const size_t krn = (size_t)(tn * 64 + w * 16 + r16) * 1536;
        const short8 n0 = *reinterpret_cast<const short8*>(kb + krn + g8);
        const short8 n1 = *reinterpret_cast<const short8*>(kb + krn + 32 + g8);
        f32x4 acc = __builtin_amdgcn_mfma_f32_16x16x32_bf16(af0, c0, zero4, 0, 0, 0);
        acc = __builtin_amdgcn_mfma_f32_16x16x32_bf16(af1, c1, acc, 0, 0, 0);
        const int col = t * 64 + w * 16 + r16;
        if (rq < 8) {
#pragma unroll
            for (int j = 0; j < 4; ++j)
                sc[rq + j][col] = __half_as_ushort(__float2half(acc[j] * 0.125f));
        }
        c0 = n0; c1 = n1;
    }
    __syncthreads();

    const ull ltm = (1ull << lane) - 1ull;
    for (int round = 0; round < 2; ++round) {
        const int q = w * 2 + round;
        unsigned key[36];
        unsigned kmax = 0;
#pragma unroll
        for (int j = 0; j < 36; ++j) {
            unsigned hb = sc[q][lane + j * 64];
            key[j] = h2key(hb);
            kmax = key[j] > kmax ? key[j] : kmax;
        }
#pragma unroll
        for (int off = 32; off; off >>= 1) {
            unsigned o = (unsigned)__shfl_xor((int)kmax, off);
            kmax = o > kmax ? o : kmax;
        }
        // exact 32nd-largest key: MSB binary search, ballot-SALU counting
        unsigned thr = 0;
        for (int bit = 15; bit >= 0; --bit) {
            unsigned cand = thr | (1u << bit);
            int c = 0;
#pragma unroll
            for (int j = 0; j < 36; ++j)
                c += (int)__popcll(__ballot(key[j] >= cand));
            if (c >= 32) { thr = cand; if (c == 32) break; }
        }
        // strict pass: keys > thr
        int tot = 0;
#pragma unroll
        for (int j = 0; j < 36; ++j) {
            bool p = key[j] > thr;
            ull m = __ballot(p);
            if (p) {
                int pos = tot + (int)__popcll(m & ltm);
                ilist[q][pos] = j * 64 + lane;
                wlist[q][pos] = key2f(key[j]);
            }
            tot += (int)__popcll(m);
        }
        // tie pass: keys == thr in ascending index order
        const int r = 32 - tot;
        const float tv = key2f(thr);
        int t2 = 0;
#pragma unroll
        for (int j = 0; j < 36; ++j) {
            bool p = (key[j] == thr) && (t2 < 32);
            ull m = __ballot(p);
            if (p) {
                int pos = t2 + (int)__popcll(m & ltm);
                if (pos < r) {
                    ilist[q][tot + pos] = j * 64 + lane;
                    wlist[q][tot + pos] = tv;
                }
            }
            t2 += (int)__popcll(m);
        }
        const float mf = key2f(kmax);
        float e = 0.f;
        if (lane < 32) e = expf(wlist[q][lane] - mf);
        float sum = e;
#pragma unroll
        for (int off = 32; off; off >>= 1) sum += __shfl_xor(sum, off);
        if (lane < 32) wlist[q][lane] = e / sum;
        float o = 0.f;
        const u16* vb = Vb + (size_t)b * 2304 * 1536 + h * 64 + lane;
#pragma unroll 8
        for (int i = 0; i < 32; ++i)
            o += wlist[q][i] * bf2f(vb[(size_t)ilist[q][i] * 1536]);
        out[((size_t)(b * 2304 + q0 + q)) * 512 + h * 64 + lane] = f2bf(o);
    }
}

// ---------------- workspace layout (bytes) ---------------
static constexpr size_t O_WQKVC = 0;                       // [1536,768]
static constexpr size_t O_WOC   = O_WQKVC + 2359296;       // [768,512]
static constexpr size_t O_W1C   = O_WOC + 786432;          // [6144,768]
static constexpr size_t O_W2C   = O_W1C + 9437184;         // [768,3072]
static constexpr size_t O_WQKVI = O_W2C + 4718592;         // [1536,512]
static constexpr size_t O_WOI   = O_WQKVI + 1572864;       // [512,512]
static constexpr size_t O_WQX   = O_WOI + 524288;          // [512,512]
static constexpr size_t O_WKVX  = O_WQX + 524288;          // [1024,768]
static constexpr size_t O_WOX   = O_WKVX + 1572864;        // [512,512]
static constexpr size_t O_W1I   = O_WOX + 524288;          // [4096,512]
static constexpr size_t O_W2I   = O_W1I + 4194304;         // [512,2048]
static constexpr size_t O_CF16  = O_W2I + 2097152;         // [512,768] bf16
static constexpr size_t O_H     = O_CF16 + 786432;         // [4608,512] f32
static constexpr size_t O_H2    = O_H + 9437184;           // [4608,512] f32
static constexpr size_t O_S     = O_H2 + 9437184;
// ctx phase
static constexpr size_t O_CN16  = O_S;                     // [512,768] bf16
static constexpr size_t O_QKVC  = O_CN16 + 786432;         // [512,1536] bf16
static constexpr size_t O_VTC   = O_QKVC + 1572864;        // [2,512,256] bf16
static constexpr size_t O_AO16  = O_VTC + 524288;          // [512,512] bf16
static constexpr size_t O_CBUF  = O_AO16 + 524288;         // [512,768] f32
static constexpr size_t O_C16   = O_CBUF + 1572864;        // [512,768] bf16
static constexpr size_t O_FFH   = O_C16 + 786432;          // [512,6144] bf16
static constexpr size_t O_AG16  = O_FFH + 6291456;         // [512,3072] bf16
// img phase 1
static constexpr size_t O_XLN   = O_S;                     // [4608,512] bf16
static constexpr size_t O_QKVI  = O_XLN + 4718592;         // [4608,1536] bf16
static constexpr size_t O_TO16  = O_QKVI + 14155776;       // [4608,512] bf16
// img phase 2
static constexpr size_t O_H2LN  = O_S;                     // [4608,512] bf16
static constexpr size_t O_XQ    = O_H2LN + 4718592;        // [4608,512] bf16
static constexpr size_t O_KVX   = O_XQ + 4718592;          // [512,1024] bf16
static constexpr size_t O_VTX   = O_KVX + 1048576;         // [2,512,256] bf16
static constexpr size_t O_XO16  = O_VTX + 524288;          // [4608,512] bf16
// ff phase
static constexpr size_t O_H3    = O_S;                     // [4608,512] bf16
static constexpr size_t O_FFIH  = O_H3 + 4718592;          // [4608,4096] bf16
static constexpr size_t O_AGI   = O_FFIH + 37748736;       // [4608,2048] bf16

extern "C" void kernel_launch(void* const* d_in, const int* in_sizes, int n_in,
                              void* d_out, int out_size, void* d_ws, size_t ws_size,
                              hipStream_t stream) {
    (void)in_sizes; (void)n_in; (void)out_size; (void)ws_size;
    const float* x      = (const float*)d_in[0];
    const float* ctx    = (const float*)d_in[1];
    const float* ctx_wq = (const float*)d_in[3];
    const float* ctx_wk = (const float*)d_in[4];
    const float* ctx_wv = (const float*)d_in[5];
    const float* ctx_wo = (const float*)d_in[6];
    const float* ctx_bo = (const float*)d_in[7];
    const float* cn_g   = (const float*)d_in[8];
    const float* cn_b   = (const float*)d_in[9];
    const float* im_wq  = (const float*)d_in[10];
    const float* im_wk  = (const float*)d_in[11];
    const float* im_wv  = (const float*)d_in[12];
    const float* im_wo  = (const float*)d_in[13];
    const float* im_bo  = (const float*)d_in[14];
    const float* xc_wq  = (const float*)d_in[15];
    const float* xc_wk  = (const float*)d_in[16];
    const float* xc_wv  = (const float*)d_in[17];
    const float* xc_wo  = (const float*)d_in[18];
    const float* xc_bo  = (const float*)d_in[19];
    const float* ffc_w1 = (const float*)d_in[20];
    const float* ffc_b1 = (const float*)d_in[21];
    const float* ffc_w2 = (const float*)d_in[22];
    const float* ffc_b2 = (const float*)d_in[23];
    const float* ffi_w1 = (const float*)d_in[24];
    const float* ffi_b1 = (const float*)d_in[25];
    const float* ffi_w2 = (const float*)d_in[26];
    const float* ffi_b2 = (const float*)d_in[27];
    const float* n1_g   = (const float*)d_in[28];
    const float* n1_b   = (const float*)d_in[29];
    const float* n2_g   = (const float*)d_in[30];
    const float* n2_b   = (const float*)d_in[31];
    const float* n3_g   = (const float*)d_in[32];
    const float* n3_b   = (const float*)d_in[33];
    char* ws = (char*)d_ws;
    float* out = (float*)d_out;
    auto Wp = [&](size_t off) { return (u16*)(ws + off); };
    auto Fp = [&](size_t off) { return (float*)(ws + off); };
    dim3 tb(32, 8);

    // ---- one batched weight transpose+cast (QKV fused along N) ----
    TBatch tbat;
    const float* srcs[16] = {ctx_wq, ctx_wk, ctx_wv, ctx_wo, ffc_w1, ffc_w2,
                             im_wq, im_wk, im_wv, im_wo, xc_wq, xc_wk, xc_wv,
                             xc_wo, ffi_w1, ffi_w2};
    const size_t dsts[16] = {O_WQKVC, O_WQKVC + 786432, O_WQKVC + 1572864, O_WOC,
                             O_W1C, O_W2C,
                             O_WQKVI, O_WQKVI + 524288, O_WQKVI + 1048576, O_WOI,
                             O_WQX, O_WKVX, O_WKVX + 786432, O_WOX,
                             O_W1I, O_W2I};
    const int Ks[16] = {768, 768, 768, 512, 768, 3072, 512, 512, 512, 512,
                        512, 768, 768, 512, 512, 2048};
    const int Ns[16] = {512, 512, 512, 768, 6144, 768, 512, 512, 512, 512,
                        512, 512, 512, 512, 4096, 512};
    int acc = 0;
    for (int i = 0; i < 16; ++i) {
        tbat.src[i] = srcs[i];
        tbat.dst[i] = Wp(dsts[i]);
        tbat.K[i] = Ks[i];
        tbat.N[i] = Ns[i];
        tbat.start[i] = acc;
        acc += (Ns[i] >> 5) * (Ks[i] >> 5);
    }
    tbat.start[16] = acc;
    k_transpose_cast_batch<<<acc, tb, 0, stream>>>(tbat);

    // ---- context path ----
    k_ln_bf16<<<128, 256, 0, stream>>>(ctx, cn_g, cn_b, Wp(O_CN16), 768);
    gemm_bt<<<dim3(12, 4), 256, 0, stream>>>(Wp(O_CN16), Wp(O_WQKVC), nullptr, nullptr, nullptr, Wp(O_QKVC), 512, 1536, 768);
    k_vtrans16<<<dim3(16, 8, 2), tb, 0, stream>>>(Wp(O_QKVC), 1536, 1024, Wp(O_VTC));
    k_attn_mfma<<<256, 256, 0, stream>>>(Wp(O_QKVC), 1536, Wp(O_QKVC) + 512, 1536, Wp(O_VTC), Wp(O_AO16), 256);
    gemm_bt<<<dim3(6, 4), 256, 0, stream>>>(Wp(O_AO16), Wp(O_WOC), ctx_bo, ctx, Fp(O_CBUF), Wp(O_C16), 512, 768, 512);
    gemm_bt<<<dim3(48, 4), 256, 0, stream>>>(Wp(O_C16), Wp(O_W1C), ffc_b1, nullptr, nullptr, Wp(O_FFH), 512, 6144, 768);
    k_geglu<<<1536, 256, 0, stream>>>(Wp(O_FFH), Wp(O_AG16), 512, 3072);
    gemm_bt<<<dim3(6, 4), 256, 0, stream>>>(Wp(O_AG16), Wp(O_W2C), ffc_b2, Fp(O_CBUF), nullptr, Wp(O_CF16), 512, 768, 3072);

    // ---- image: top-k self-attention ----
    k_ln_bf16<<<1152, 256, 0, stream>>>(x, n1_g, n1_b, Wp(O_XLN), 512);
    gemm_bt<<<dim3(12, 36), 256, 0, stream>>>(Wp(O_XLN), Wp(O_WQKVI), nullptr, nullptr, nullptr, Wp(O_QKVI), 4608, 1536, 512);
    k_topk_attn<<<4608, 256, 0, stream>>>(Wp(O_QKVI), Wp(O_QKVI) + 512, Wp(O_QKVI) + 1024, Wp(O_TO16));
    gemm_bt<<<dim3(4, 36), 256, 0, stream>>>(Wp(O_TO16), Wp(O_WOI), im_bo, x, Fp(O_H), nullptr, 4608, 512, 512);

    // ---- image -> context cross-attention ----
    k_ln_bf16<<<1152, 256, 0, stream>>>(Fp(O_H), n2_g, n2_b, Wp(O_H2LN), 512);
    gemm_bt<<<dim3(4, 36), 256, 0, stream>>>(Wp(O_H2LN), Wp(O_WQX), nullptr, nullptr, nullptr, Wp(O_XQ), 4608, 512, 512);
    gemm_bt<<<dim3(8, 4), 256, 0, stream>>>(Wp(O_CF16), Wp(O_WKVX), nullptr, nullptr, nullptr, Wp(O_KVX), 512, 1024, 768);
    k_vtrans16<<<dim3(16, 8, 2), tb, 0, stream>>>(Wp(O_KVX), 1024, 512, Wp(O_VTX));
    k_attn_mfma<<<2304, 256, 0, stream>>>(Wp(O_XQ), 512, Wp(O_KVX), 1024, Wp(O_VTX), Wp(O_XO16), 2304);
    gemm_bt<<<dim3(4, 36), 256, 0, stream>>>(Wp(O_XO16), Wp(O_WOX), xc_bo, Fp(O_H), Fp(O_H2), nullptr, 4608, 512, 512);

    // ---- image GEGLU FF ----
    k_ln_bf16<<<1152, 256, 0, stream>>>(Fp(O_H2), n3_g, n3_b, Wp(O_H3), 512);
    gemm_bt<<<dim3(32, 36), 256, 0, stream>>>(Wp(O_H3), Wp(O_W1I), ffi_b1, nullptr, nullptr, Wp(O_FFIH), 4608, 4096, 512);
    k_geglu<<<4096, 256, 0, stream>>>(Wp(O_FFIH), Wp(O_AGI), 4608, 2048);
    gemm_bt<<<dim3(4, 36), 256, 0, stream>>>(Wp(O_AGI), Wp(O_W2I), ffi_b2, Fp(O_H2), out, nullptr, 4608, 512, 2048);
}

// Round 5
// 681.438 us; speedup vs baseline: 5.1338x; 1.1540x over previous
//
#include <hip/hip_runtime.h>
#include <hip/hip_bf16.h>
#include <hip/hip_fp16.h>
#include <cmath>

typedef unsigned short u16;
typedef unsigned long long ull;
typedef __attribute__((ext_vector_type(8))) short short8;
typedef __attribute__((ext_vector_type(4))) float f32x4;
typedef __attribute__((ext_vector_type(4))) unsigned short u16x4;

__device__ __forceinline__ u16 f2bf(float x) {
    unsigned u = __float_as_uint(x);
    u += 0x7fffu + ((u >> 16) & 1u);
    return (u16)(u >> 16);
}
__device__ __forceinline__ float bf2f(u16 b) {
    return __uint_as_float(((unsigned)b) << 16);
}

// sortable-u16 key <-> f16 bits (order-preserving map)
__device__ __forceinline__ unsigned h2key(unsigned hb) {
    return (hb & 0x8000u) ? (hb ^ 0xFFFFu) : (hb | 0x8000u);
}
__device__ __forceinline__ float key2f(unsigned k) {
    unsigned hb = (k & 0x8000u) ? (k ^ 0x8000u) : (k ^ 0xFFFFu);
    return __half2float(__ushort_as_half((unsigned short)hb));
}

// async global->LDS 16B per lane: dest = ldsbase + lane*16 (wave-uniform base)
typedef __attribute__((address_space(3))) unsigned int as3_uint;
typedef __attribute__((address_space(1))) unsigned int as1_uint;
__device__ __forceinline__ void gload_lds16(const u16* g, u16* l) {
    __builtin_amdgcn_global_load_lds(
        (as1_uint*)(unsigned long long)(const void*)g,
        (as3_uint*)(unsigned int)(unsigned long long)(const void*)l,
        16, 0, 0);
}

// ---------------- batched transpose+cast: w[K][N] f32 -> wt[N][K] bf16 --------
struct TBatch {
    const float* src[16];
    u16* dst[16];
    int K[16];
    int N[16];
    int start[17];
};

__global__ void k_transpose_cast_batch(TBatch tb) {
    __shared__ float tile[32][33];
    int t = blockIdx.x;
    int m = 0;
    while (t >= tb.start[m + 1]) ++m;
    int rel = t - tb.start[m];
    const int K = tb.K[m], N = tb.N[m];
    const int ntx = N >> 5;
    const int n0 = (rel % ntx) * 32, k0 = (rel / ntx) * 32;
    const float* __restrict__ in = tb.src[m];
    u16* __restrict__ out = tb.dst[m];
    int tx = threadIdx.x, ty = threadIdx.y;
#pragma unroll
    for (int j = 0; j < 4; ++j)
        tile[ty + j * 8][tx] = in[(size_t)(k0 + ty + j * 8) * N + n0 + tx];
    __syncthreads();
#pragma unroll
    for (int j = 0; j < 4; ++j)
        out[(size_t)(n0 + ty + j * 8) * K + k0 + tx] = f2bf(tile[tx][ty + j * 8]);
}

// -------- V transpose (bf16 in): in[b*256+k][stride] col coloff+d -> out[b][512][256]
__global__ void k_vtrans16(const u16* __restrict__ in, int stride, int coloff,
                           u16* __restrict__ out) {
    __shared__ int tile[32][33];
    int tx = threadIdx.x, ty = threadIdx.y;
    int d0 = blockIdx.x * 32, k0 = blockIdx.y * 32, b = blockIdx.z;
#pragma unroll
    for (int j = 0; j < 4; ++j)
        tile[ty + j * 8][tx] = in[(size_t)(b * 256 + k0 + ty + j * 8) * stride + coloff + d0 + tx];
    __syncthreads();
#pragma unroll
    for (int j = 0; j < 4; ++j)
        out[(size_t)(b * 512 + d0 + ty + j * 8) * 256 + k0 + tx] = (u16)tile[tx][ty + j * 8];
}

// ---------------- LayerNorm (fp32 in) -> bf16 out; 4 rows/block, 1 wave/row ----
__global__ __launch_bounds__(256)
void k_ln_bf16(const float* __restrict__ in, const float* __restrict__ gam,
               const float* __restrict__ bet, u16* __restrict__ out, int F) {
    int lane = threadIdx.x & 63, w = threadIdx.x >> 6;
    int row = blockIdx.x * 4 + w;
    const float* r = in + (size_t)row * F;
    float s = 0.f, s2 = 0.f;
    for (int j = lane; j < F; j += 64) { float v = r[j]; s += v; s2 += v * v; }
#pragma unroll
    for (int off = 32; off; off >>= 1) { s += __shfl_xor(s, off); s2 += __shfl_xor(s2, off); }
    float mean = s / F;
    float var  = s2 / F - mean * mean;
    float inv  = 1.f / sqrtf(var + 1e-5f);
    u16* o = out + (size_t)row * F;
    for (int j = lane; j < F; j += 64)
        o[j] = f2bf((r[j] - mean) * inv * gam[j] + bet[j]);
}

// ---------------- GEGLU: hid[M,2F] bf16 -> out[M,F] bf16 (a * gelu_exact(g)) --
__global__ __launch_bounds__(256)
void k_geglu(const u16* __restrict__ hid, u16* __restrict__ out, int Mrows, int F) {
    const int F4 = F >> 2;
    size_t total = (size_t)Mrows * F4;
    for (size_t i4 = (size_t)blockIdx.x * blockDim.x + threadIdx.x; i4 < total;
         i4 += (size_t)gridDim.x * blockDim.x) {
        size_t r = i4 / F4, c4 = (i4 - r * F4) * 4;
        u16x4 a4 = *reinterpret_cast<const u16x4*>(hid + r * 2 * F + c4);
        u16x4 g4 = *reinterpret_cast<const u16x4*>(hid + r * 2 * F + F + c4);
        u16x4 o4;
#pragma unroll
        for (int j = 0; j < 4; ++j) {
            float a = bf2f(a4[j]), g = bf2f(g4[j]);
            float ge = 0.5f * g * (1.f + erff(g * 0.70710678118654752f));
            o4[j] = f2bf(a * ge);
        }
        *reinterpret_cast<u16x4*>(out + r * F + c4) = o4;
    }
}

// ------- bf16 MFMA GEMM (templated tile): C[M,N] = A[M,K] @ Bt[N,K]^T ---------
// 4 waves as 2x2; global_load_lds width-16 staging; K-step 32.
template <int BM, int BN>
__global__ __launch_bounds__(256)
void gemm_bt(const u16* __restrict__ A, const u16* __restrict__ Bt,
             const float* __restrict__ bias, const float* __restrict__ res,
             float* __restrict__ out32, u16* __restrict__ out16,
             int M, int N, int K) {
    constexpr int WM = BM / 2, WN = BN / 2, FM = WM / 16, FN = WN / 16;
    __shared__ __align__(16) u16 As[BM * 32];
    __shared__ __align__(16) u16 Bs[BN * 32];
    const int tid = threadIdx.x;
    const int lane = tid & 63;
    const int wid = tid >> 6;
    const int wr = wid >> 1, wc = wid & 1;
    const int m0 = blockIdx.y * BM, n0 = blockIdx.x * BN;
    const int r16 = lane & 15;
    const int g8  = (lane >> 4) * 8;
    const int w16 = wid * 16;
    const int ln4 = lane >> 2;
    const int cb8 = (lane & 3) * 8;

    const f32x4 zero4 = {0.f, 0.f, 0.f, 0.f};
    f32x4 acc[FM][FN];
#pragma unroll
    for (int m = 0; m < FM; ++m)
#pragma unroll
        for (int n = 0; n < FN; ++n) acc[m][n] = zero4;

    for (int k0 = 0; k0 < K; k0 += 32) {
#pragma unroll
        for (int p = 0; p < BM / 64; ++p) {
            const int rb = p * 64 + w16;
            gload_lds16(A + (size_t)(m0 + rb + ln4) * K + k0 + cb8, &As[rb * 32]);
        }
#pragma unroll
        for (int p = 0; p < BN / 64; ++p) {
            const int rb = p * 64 + w16;
            gload_lds16(Bt + (size_t)(n0 + rb + ln4) * K + k0 + cb8, &Bs[rb * 32]);
        }
        __syncthreads();
        short8 af[FM], bfr[FN];
#pragma unroll
        for (int m = 0; m < FM; ++m)
            af[m] = *reinterpret_cast<const short8*>(&As[(wr * WM + m * 16 + r16) * 32 + g8]);
#pragma unroll
        for (int n = 0; n < FN; ++n)
            bfr[n] = *reinterpret_cast<const short8*>(&Bs[(wc * WN + n * 16 + r16) * 32 + g8]);
#pragma unroll
        for (int m = 0; m < FM; ++m)
#pragma unroll
            for (int n = 0; n < FN; ++n)
                acc[m][n] = __builtin_amdgcn_mfma_f32_16x16x32_bf16(af[m], bfr[n], acc[m][n], 0, 0, 0);
        __syncthreads();
    }

    const int rg = (lane >> 4) * 4;
#pragma unroll
    for (int m = 0; m < FM; ++m) {
#pragma unroll
        for (int n = 0; n < FN; ++n) {
#pragma unroll
            for (int j = 0; j < 4; ++j) {
                int row = m0 + wr * WM + m * 16 + rg + j;
                int col = n0 + wc * WN + n * 16 + r16;
                float v = acc[m][n][j];
                if (bias) v += bias[col];
                size_t off = (size_t)row * N + col;
                if (res) v += res[off];
                if (out32) out32[off] = v;
                if (out16) out16[off] = f2bf(v);
            }
        }
    }
}

// ---------------- MFMA SDPA attention, 256 keys, 8 heads, dh=64 ----------------
__global__ __launch_bounds__(256)
void k_attn_mfma(const u16* __restrict__ Qb, int sq, const u16* __restrict__ Kb,
                 int sk, const u16* __restrict__ VT, u16* __restrict__ out, int NQ) {
    __shared__ float sc[16][268];
    __shared__ u16   pb[16][268];
    const int tid = threadIdx.x, lane = tid & 63, w = tid >> 6;
    const int nqb = NQ >> 4;
    const int q0 = (blockIdx.x % nqb) << 4;
    const int h = (blockIdx.x / nqb) & 7;
    const int b = blockIdx.x / (nqb * 8);
    const int r16 = lane & 15, g8 = (lane >> 4) * 8, rq = (lane >> 4) * 4;

    const size_t qrow = ((size_t)(b * NQ + q0 + r16)) * sq + h * 64;
    const short8 af0 = *reinterpret_cast<const short8*>(Qb + qrow + g8);
    const short8 af1 = *reinterpret_cast<const short8*>(Qb + qrow + 32 + g8);
    const u16* kb = Kb + (size_t)b * 256 * sk + h * 64;
    const f32x4 zero4 = {0.f, 0.f, 0.f, 0.f};
#pragma unroll
    for (int t = 0; t < 4; ++t) {
        const size_t krow = (size_t)(t * 64 + w * 16 + r16) * sk;
        const short8 bf0 = *reinterpret_cast<const short8*>(kb + krow + g8);
        const short8 bf1 = *reinterpret_cast<const short8*>(kb + krow + 32 + g8);
        f32x4 acc = __builtin_amdgcn_mfma_f32_16x16x32_bf16(af0, bf0, zero4, 0, 0, 0);
        acc = __builtin_amdgcn_mfma_f32_16x16x32_bf16(af1, bf1, acc, 0, 0, 0);
        const int col = t * 64 + w * 16 + r16;
#pragma unroll
        for (int j = 0; j < 4; ++j) sc[rq + j][col] = acc[j] * 0.125f;
    }
    __syncthreads();
#pragma unroll
    for (int qi = 0; qi < 4; ++qi) {
        const int q = w * 4 + qi;
        float4 v = *reinterpret_cast<const float4*>(&sc[q][lane * 4]);
        float m = fmaxf(fmaxf(v.x, v.y), fmaxf(v.z, v.w));
#pragma unroll
        for (int off = 32; off; off >>= 1) m = fmaxf(m, __shfl_xor(m, off));
        float e0 = expf(v.x - m), e1 = expf(v.y - m), e2 = expf(v.z - m), e3 = expf(v.w - m);
        float sum = e0 + e1 + e2 + e3;
#pragma unroll
        for (int off = 32; off; off >>= 1) sum += __shfl_xor(sum, off);
        float inv = 1.f / sum;
        u16x4 p4;
        p4[0] = f2bf(e0 * inv); p4[1] = f2bf(e1 * inv);
        p4[2] = f2bf(e2 * inv); p4[3] = f2bf(e3 * inv);
        *reinterpret_cast<u16x4*>(&pb[q][lane * 4]) = p4;
    }
    __syncthreads();
    f32x4 o = zero4;
    const u16* vt = VT + ((size_t)(b * 512 + h * 64 + w * 16 + r16)) * 256;
#pragma unroll
    for (int kk = 0; kk < 8; ++kk) {
        const short8 pa = *reinterpret_cast<const short8*>(&pb[r16][kk * 32 + g8]);
        const short8 vv = *reinterpret_cast<const short8*>(vt + kk * 32 + g8);
        o = __builtin_amdgcn_mfma_f32_16x16x32_bf16(pa, vv, o, 0, 0, 0);
    }
#pragma unroll
    for (int j = 0; j < 4; ++j)
        out[((size_t)(b * NQ + q0 + rq + j)) * 512 + h * 64 + w * 16 + r16] = f2bf(o[j]);
}

// ---------------- top-32 sparse self-attention, N=2304, dh=64 ------------------
// 16 queries/block (full MFMA M-dim). Q,K,V packed bf16 rows stride 1536.
__global__ __launch_bounds__(256)
void k_topk_attn(const u16* __restrict__ Qb, const u16* __restrict__ Kb,
                 const u16* __restrict__ Vb, u16* __restrict__ out) {
    __shared__ u16   sc[16][2312];
    __shared__ int   ilist[16][32];
    __shared__ float wlist[16][32];
    const int tid = threadIdx.x, lane = tid & 63, w = tid >> 6;
    const int bh = blockIdx.x / 144;
    const int b = bh >> 3, h = bh & 7;
    const int q0 = (blockIdx.x % 144) * 16;
    const int r16 = lane & 15;
    const int g8  = (lane >> 4) * 8;
    const int rq  = (lane >> 4) * 4;

    const size_t qrow = ((size_t)(b * 2304 + q0 + r16)) * 1536 + h * 64;
    const short8 af0 = *reinterpret_cast<const short8*>(Qb + qrow + g8);
    const short8 af1 = *reinterpret_cast<const short8*>(Qb + qrow + 32 + g8);

    const u16* kb = Kb + (size_t)b * 2304 * 1536 + h * 64;
    const f32x4 zero4 = {0.f, 0.f, 0.f, 0.f};
    // score phase, 2-deep prefetch (4 loads in flight)
    const size_t kr0 = (size_t)(w * 16 + r16) * 1536;
    const size_t kr1 = (size_t)(64 + w * 16 + r16) * 1536;
    short8 a0 = *reinterpret_cast<const short8*>(kb + kr0 + g8);
    short8 a1 = *reinterpret_cast<const short8*>(kb + kr0 + 32 + g8);
    short8 b0 = *reinterpret_cast<const short8*>(kb + kr1 + g8);
    short8 b1 = *reinterpret_cast<const short8*>(kb + kr1 + 32 + g8);
    for (int t = 0; t < 36; ++t) {
        const int tn = (t < 34) ? t + 2 : t;
        const size_t krn = (size_t)(tn * 64 + w * 16 + r16) * 1536;
        const short8 n0 = *reinterpret_cast<const short8*>(kb + krn + g8);
        const short8 n1 = *reinterpret_cast<const short8*>(kb + krn + 32 + g8);
        f32x4 acc = __builtin_amdgcn_mfma_f32_16x16x32_bf16(af0, a0, zero4, 0, 0, 0);
        acc = __builtin_amdgcn_mfma_f32_16x16x32_bf16(af1, a1, acc, 0, 0, 0);
        const int col = t * 64 + w * 16 + r16;
#pragma unroll
        for (int j = 0; j < 4; ++j)
            sc[rq + j][col] = __half_as_ushort(__float2half(acc[j] * 0.125f));
        a0 = b0; a1 = b1; b0 = n0; b1 = n1;
    }
    __syncthreads();

    const ull ltm = (1ull << lane) - 1ull;
    for (int round = 0; round < 4; ++round) {
        const int q = w * 4 + round;
        unsigned key[36];
        unsigned kmax = 0;
#pragma unroll
        for (int j = 0; j < 36; ++j) {
            unsigned hb = sc[q][lane + j * 64];
            key[j] = h2key(hb);
            kmax = key[j] > kmax ? key[j] : kmax;
        }
#pragma unroll
        for (int off = 32; off; off >>= 1) {
            unsigned o = (unsigned)__shfl_xor((int)kmax, off);
            kmax = o > kmax ? o : kmax;
        }
        // exact 32nd-largest key: MSB binary search, ballot counting
        unsigned thr = 0;
        for (int bit = 15; bit >= 0; --bit) {
            unsigned cand = thr | (1u << bit);
            int c = 0;
#pragma unroll
            for (int j = 0; j < 36; ++j)
                c += (int)__popcll(__ballot(key[j] >= cand));
            if (c >= 32) { thr = cand; if (c == 32) break; }
        }
        // strict pass: keys > thr
        int tot = 0;
#pragma unroll
        for (int j = 0; j < 36; ++j) {
            bool p = key[j] > thr;
            ull m = __ballot(p);
            if (p) {
                int pos = tot + (int)__popcll(m & ltm);
                ilist[q][pos] = j * 64 + lane;
                wlist[q][pos] = key2f(key[j]);
            }
            tot += (int)__popcll(m);
        }
        // tie pass: keys == thr in ascending index order
        const int r = 32 - tot;
        const float tv = key2f(thr);
        int t2 = 0;
#pragma unroll
        for (int j = 0; j < 36; ++j) {
            bool p = (key[j] == thr) && (t2 < 32);
            ull m = __ballot(p);
            if (p) {
                int pos = t2 + (int)__popcll(m & ltm);
                if (pos < r) {
                    ilist[q][tot + pos] = j * 64 + lane;
                    wlist[q][tot + pos] = tv;
                }
            }
            t2 += (int)__popcll(m);
        }
        const float mf = key2f(kmax);
        float e = 0.f;
        if (lane < 32) e = expf(wlist[q][lane] - mf);
        float sum = e;
#pragma unroll
        for (int off = 32; off; off >>= 1) sum += __shfl_xor(sum, off);
        if (lane < 32) wlist[q][lane] = e / sum;
        // PV gather: batch all 32 row loads, then reduce
        const u16* vb = Vb + (size_t)b * 2304 * 1536 + h * 64 + lane;
        u16 vr[32];
#pragma unroll
        for (int i = 0; i < 32; ++i)
            vr[i] = vb[(size_t)ilist[q][i] * 1536];
        float o = 0.f;
#pragma unroll
        for (int i = 0; i < 32; ++i)
            o += wlist[q][i] * bf2f(vr[i]);
        out[((size_t)(b * 2304 + q0 + q)) * 512 + h * 64 + lane] = f2bf(o);
    }
}

// ---------------- workspace layout (bytes) ---------------
static constexpr size_t O_WQKVC = 0;                       // [1536,768]
static constexpr size_t O_WOC   = O_WQKVC + 2359296;       // [768,512]
static constexpr size_t O_W1C   = O_WOC + 786432;          // [6144,768]
static constexpr size_t O_W2C   = O_W1C + 9437184;         // [768,3072]
static constexpr size_t O_WQKVI = O_W2C + 4718592;         // [1536,512]
static constexpr size_t O_WOI   = O_WQKVI + 1572864;       // [512,512]
static constexpr size_t O_WQX   = O_WOI + 524288;          // [512,512]
static constexpr size_t O_WKVX  = O_WQX + 524288;          // [1024,768]
static constexpr size_t O_WOX   = O_WKVX + 1572864;        // [512,512]
static constexpr size_t O_W1I   = O_WOX + 524288;          // [4096,512]
static constexpr size_t O_W2I   = O_W1I + 4194304;         // [512,2048]
static constexpr size_t O_CF16  = O_W2I + 2097152;         // [512,768] bf16
static constexpr size_t O_H     = O_CF16 + 786432;         // [4608,512] f32
static constexpr size_t O_H2    = O_H + 9437184;           // [4608,512] f32
static constexpr size_t O_S     = O_H2 + 9437184;
// ctx phase
static constexpr size_t O_CN16  = O_S;                     // [512,768] bf16
static constexpr size_t O_QKVC  = O_CN16 + 786432;         // [512,1536] bf16
static constexpr size_t O_VTC   = O_QKVC + 1572864;        // [2,512,256] bf16
static constexpr size_t O_AO16  = O_VTC + 524288;          // [512,512] bf16
static constexpr size_t O_CBUF  = O_AO16 + 524288;         // [512,768] f32
static constexpr size_t O_C16   = O_CBUF + 1572864;        // [512,768] bf16
static constexpr size_t O_FFH   = O_C16 + 786432;          // [512,6144] bf16
static constexpr size_t O_AG16  = O_FFH + 6291456;         // [512,3072] bf16
// img phase 1
static constexpr size_t O_XLN   = O_S;                     // [4608,512] bf16
static constexpr size_t O_QKVI  = O_XLN + 4718592;         // [4608,1536] bf16
static constexpr size_t O_TO16  = O_QKVI + 14155776;       // [4608,512] bf16
// img phase 2
static constexpr size_t O_H2LN  = O_S;                     // [4608,512] bf16
static constexpr size_t O_XQ    = O_H2LN + 4718592;        // [4608,512] bf16
static constexpr size_t O_KVX   = O_XQ + 4718592;          // [512,1024] bf16
static constexpr size_t O_VTX   = O_KVX + 1048576;         // [2,512,256] bf16
static constexpr size_t O_XO16  = O_VTX + 524288;          // [4608,512] bf16
// ff phase
static constexpr size_t O_H3    = O_S;                     // [4608,512] bf16
static constexpr size_t O_FFIH  = O_H3 + 4718592;          // [4608,4096] bf16
static constexpr size_t O_AGI   = O_FFIH + 37748736;       // [4608,2048] bf16

extern "C" void kernel_launch(void* const* d_in, const int* in_sizes, int n_in,
                              void* d_out, int out_size, void* d_ws, size_t ws_size,
                              hipStream_t stream) {
    (void)in_sizes; (void)n_in; (void)out_size; (void)ws_size;
    const float* x      = (const float*)d_in[0];
    const float* ctx    = (const float*)d_in[1];
    const float* ctx_wq = (const float*)d_in[3];
    const float* ctx_wk = (const float*)d_in[4];
    const float* ctx_wv = (const float*)d_in[5];
    const float* ctx_wo = (const float*)d_in[6];
    const float* ctx_bo = (const float*)d_in[7];
    const float* cn_g   = (const float*)d_in[8];
    const float* cn_b   = (const float*)d_in[9];
    const float* im_wq  = (const float*)d_in[10];
    const float* im_wk  = (const float*)d_in[11];
    const float* im_wv  = (const float*)d_in[12];
    const float* im_wo  = (const float*)d_in[13];
    const float* im_bo  = (const float*)d_in[14];
    const float* xc_wq  = (const float*)d_in[15];
    const float* xc_wk  = (const float*)d_in[16];
    const float* xc_wv  = (const float*)d_in[17];
    const float* xc_wo  = (const float*)d_in[18];
    const float* xc_bo  = (const float*)d_in[19];
    const float* ffc_w1 = (const float*)d_in[20];
    const float* ffc_b1 = (const float*)d_in[21];
    const float* ffc_w2 = (const float*)d_in[22];
    const float* ffc_b2 = (const float*)d_in[23];
    const float* ffi_w1 = (const float*)d_in[24];
    const float* ffi_b1 = (const float*)d_in[25];
    const float* ffi_w2 = (const float*)d_in[26];
    const float* ffi_b2 = (const float*)d_in[27];
    const float* n1_g   = (const float*)d_in[28];
    const float* n1_b   = (const float*)d_in[29];
    const float* n2_g   = (const float*)d_in[30];
    const float* n2_b   = (const float*)d_in[31];
    const float* n3_g   = (const float*)d_in[32];
    const float* n3_b   = (const float*)d_in[33];
    char* ws = (char*)d_ws;
    float* out = (float*)d_out;
    auto Wp = [&](size_t off) { return (u16*)(ws + off); };
    auto Fp = [&](size_t off) { return (float*)(ws + off); };
    dim3 tb(32, 8);

    // ---- one batched weight transpose+cast (QKV fused along N) ----
    TBatch tbat;
    const float* srcs[16] = {ctx_wq, ctx_wk, ctx_wv, ctx_wo, ffc_w1, ffc_w2,
                             im_wq, im_wk, im_wv, im_wo, xc_wq, xc_wk, xc_wv,
                             xc_wo, ffi_w1, ffi_w2};
    const size_t dsts[16] = {O_WQKVC, O_WQKVC + 786432, O_WQKVC + 1572864, O_WOC,
                             O_W1C, O_W2C,
                             O_WQKVI, O_WQKVI + 524288, O_WQKVI + 1048576, O_WOI,
                             O_WQX, O_WKVX, O_WKVX + 786432, O_WOX,
                             O_W1I, O_W2I};
    const int Ks[16] = {768, 768, 768, 512, 768, 3072, 512, 512, 512, 512,
                        512, 768, 768, 512, 512, 2048};
    const int Ns[16] = {512, 512, 512, 768, 6144, 768, 512, 512, 512, 512,
                        512, 512, 512, 512, 4096, 512};
    int acc = 0;
    for (int i = 0; i < 16; ++i) {
        tbat.src[i] = srcs[i];
        tbat.dst[i] = Wp(dsts[i]);
        tbat.K[i] = Ks[i];
        tbat.N[i] = Ns[i];
        tbat.start[i] = acc;
        acc += (Ns[i] >> 5) * (Ks[i] >> 5);
    }
    tbat.start[16] = acc;
    k_transpose_cast_batch<<<acc, tb, 0, stream>>>(tbat);

    // ---- context path ----
    k_ln_bf16<<<128, 256, 0, stream>>>(ctx, cn_g, cn_b, Wp(O_CN16), 768);
    gemm_bt<64, 64><<<dim3(24, 8), 256, 0, stream>>>(Wp(O_CN16), Wp(O_WQKVC), nullptr, nullptr, nullptr, Wp(O_QKVC), 512, 1536, 768);
    k_vtrans16<<<dim3(16, 8, 2), tb, 0, stream>>>(Wp(O_QKVC), 1536, 1024, Wp(O_VTC));
    k_attn_mfma<<<256, 256, 0, stream>>>(Wp(O_QKVC), 1536, Wp(O_QKVC) + 512, 1536, Wp(O_VTC), Wp(O_AO16), 256);
    gemm_bt<64, 64><<<dim3(12, 8), 256, 0, stream>>>(Wp(O_AO16), Wp(O_WOC), ctx_bo, ctx, Fp(O_CBUF), Wp(O_C16), 512, 768, 512);
    gemm_bt<128, 128><<<dim3(48, 4), 256, 0, stream>>>(Wp(O_C16), Wp(O_W1C), ffc_b1, nullptr, nullptr, Wp(O_FFH), 512, 6144, 768);
    k_geglu<<<1536, 256, 0, stream>>>(Wp(O_FFH), Wp(O_AG16), 512, 3072);
    gemm_bt<64, 64><<<dim3(12, 8), 256, 0, stream>>>(Wp(O_AG16), Wp(O_W2C), ffc_b2, Fp(O_CBUF), nullptr, Wp(O_CF16), 512, 768, 3072);

    // ---- image: top-k self-attention ----
    k_ln_bf16<<<1152, 256, 0, stream>>>(x, n1_g, n1_b, Wp(O_XLN), 512);
    gemm_bt<128, 128><<<dim3(12, 36), 256, 0, stream>>>(Wp(O_XLN), Wp(O_WQKVI), nullptr, nullptr, nullptr, Wp(O_QKVI), 4608, 1536, 512);
    k_topk_attn<<<2304, 256, 0, stream>>>(Wp(O_QKVI), Wp(O_QKVI) + 512, Wp(O_QKVI) + 1024, Wp(O_TO16));
    gemm_bt<128, 64><<<dim3(8, 36), 256, 0, stream>>>(Wp(O_TO16), Wp(O_WOI), im_bo, x, Fp(O_H), nullptr, 4608, 512, 512);

    // ---- image -> context cross-attention ----
    k_ln_bf16<<<1152, 256, 0, stream>>>(Fp(O_H), n2_g, n2_b, Wp(O_H2LN), 512);
    gemm_bt<128, 64><<<dim3(8, 36), 256, 0, stream>>>(Wp(O_H2LN), Wp(O_WQX), nullptr, nullptr, nullptr, Wp(O_XQ), 4608, 512, 512);
    gemm_bt<64, 64><<<dim3(16, 8), 256, 0, stream>>>(Wp(O_CF16), Wp(O_WKVX), nullptr, nullptr, nullptr, Wp(O_KVX), 512, 1024, 768);
    k_vtrans16<<<dim3(16, 8, 2), tb, 0, stream>>>(Wp(O_KVX), 1024, 512, Wp(O_VTX));
    k_attn_mfma<<<2304, 256, 0, stream>>>(Wp(O_XQ), 512, Wp(O_KVX), 1024, Wp(O_VTX), Wp(O_XO16), 2304);
    gemm_bt<128, 64><<<dim3(8, 36), 256, 0, stream>>>(Wp(O_XO16), Wp(O_WOX), xc_bo, Fp(O_H), Fp(O_H2), nullptr, 4608, 512, 512);

    // ---- image GEGLU FF ----
    k_ln_bf16<<<1152, 256, 0, stream>>>(Fp(O_H2), n3_g, n3_b, Wp(O_H3), 512);
    gemm_bt<128, 128><<<dim3(32, 36), 256, 0, stream>>>(Wp(O_H3), Wp(O_W1I), ffi_b1, nullptr, nullptr, Wp(O_FFIH), 4608, 4096, 512);
    k_geglu<<<4096, 256, 0, stream>>>(Wp(O_FFIH), Wp(O_AGI), 4608, 2048);
    gemm_bt<128, 64><<<dim3(8, 36), 256, 0, stream>>>(Wp(O_AGI), Wp(O_W2I), ffi_b2, Fp(O_H2), out, nullptr, 4608, 512, 2048);
}

// Round 6
// 571.116 us; speedup vs baseline: 6.1255x; 1.1932x over previous
//
#include <hip/hip_runtime.h>
#include <hip/hip_bf16.h>
#include <hip/hip_fp16.h>
#include <cmath>

typedef unsigned short u16;
typedef unsigned long long ull;
typedef __attribute__((ext_vector_type(8))) short short8;
typedef __attribute__((ext_vector_type(4))) float f32x4;
typedef __attribute__((ext_vector_type(4))) unsigned short u16x4;

__device__ __forceinline__ u16 f2bf(float x) {
    unsigned u = __float_as_uint(x);
    u += 0x7fffu + ((u >> 16) & 1u);
    return (u16)(u >> 16);
}
__device__ __forceinline__ float bf2f(u16 b) {
    return __uint_as_float(((unsigned)b) << 16);
}

// sortable-u16 key <-> f16 bits (order-preserving map)
__device__ __forceinline__ unsigned h2key(unsigned hb) {
    return (hb & 0x8000u) ? (hb ^ 0xFFFFu) : (hb | 0x8000u);
}
__device__ __forceinline__ float key2f(unsigned k) {
    unsigned hb = (k & 0x8000u) ? (k ^ 0x8000u) : (k ^ 0xFFFFu);
    return __half2float(__ushort_as_half((unsigned short)hb));
}

// async global->LDS 16B per lane: dest = ldsbase + lane*16 (wave-uniform base)
typedef __attribute__((address_space(3))) unsigned int as3_uint;
typedef __attribute__((address_space(1))) unsigned int as1_uint;
__device__ __forceinline__ void gload_lds16(const u16* g, u16* l) {
    __builtin_amdgcn_global_load_lds(
        (as1_uint*)(unsigned long long)(const void*)g,
        (as3_uint*)(unsigned int)(unsigned long long)(const void*)l,
        16, 0, 0);
}

__device__ __forceinline__ float gelu_exact(float g) {
    return 0.5f * g * (1.f + erff(g * 0.70710678118654752f));
}

// ---------------- batched transpose+cast: w[K][N] f32 -> wt[N][K] bf16 --------
struct TBatch {
    const float* src[16];
    u16* dst[16];
    int K[16];
    int N[16];
    int start[17];
};

__global__ void k_transpose_cast_batch(TBatch tb) {
    __shared__ float tile[32][33];
    int t = blockIdx.x;
    int m = 0;
    while (t >= tb.start[m + 1]) ++m;
    int rel = t - tb.start[m];
    const int K = tb.K[m], N = tb.N[m];
    const int ntx = N >> 5;
    const int n0 = (rel % ntx) * 32, k0 = (rel / ntx) * 32;
    const float* __restrict__ in = tb.src[m];
    u16* __restrict__ out = tb.dst[m];
    int tx = threadIdx.x, ty = threadIdx.y;
#pragma unroll
    for (int j = 0; j < 4; ++j)
        tile[ty + j * 8][tx] = in[(size_t)(k0 + ty + j * 8) * N + n0 + tx];
    __syncthreads();
#pragma unroll
    for (int j = 0; j < 4; ++j)
        out[(size_t)(n0 + ty + j * 8) * K + k0 + tx] = f2bf(tile[tx][ty + j * 8]);
}

// -------- V transpose (bf16 in): in[b*256+k][stride] col coloff+d -> out[b][512][256]
__global__ void k_vtrans16(const u16* __restrict__ in, int stride, int coloff,
                           u16* __restrict__ out) {
    __shared__ int tile[32][33];
    int tx = threadIdx.x, ty = threadIdx.y;
    int d0 = blockIdx.x * 32, k0 = blockIdx.y * 32, b = blockIdx.z;
#pragma unroll
    for (int j = 0; j < 4; ++j)
        tile[ty + j * 8][tx] = in[(size_t)(b * 256 + k0 + ty + j * 8) * stride + coloff + d0 + tx];
    __syncthreads();
#pragma unroll
    for (int j = 0; j < 4; ++j)
        out[(size_t)(b * 512 + d0 + ty + j * 8) * 256 + k0 + tx] = (u16)tile[tx][ty + j * 8];
}

// ---------------- LayerNorm (fp32 in) -> bf16 out; float4-vectorized ----------
__global__ __launch_bounds__(256)
void k_ln_bf16(const float* __restrict__ in, const float* __restrict__ gam,
               const float* __restrict__ bet, u16* __restrict__ out, int F) {
    int lane = threadIdx.x & 63, w = threadIdx.x >> 6;
    int row = blockIdx.x * 4 + w;
    const int F4 = F >> 2;
    const float4* r4 = reinterpret_cast<const float4*>(in + (size_t)row * F);
    const float4* g4 = reinterpret_cast<const float4*>(gam);
    const float4* b4 = reinterpret_cast<const float4*>(bet);
    float s = 0.f, s2 = 0.f;
    for (int j = lane; j < F4; j += 64) {
        float4 v = r4[j];
        s += v.x + v.y + v.z + v.w;
        s2 += v.x * v.x + v.y * v.y + v.z * v.z + v.w * v.w;
    }
#pragma unroll
    for (int off = 32; off; off >>= 1) { s += __shfl_xor(s, off); s2 += __shfl_xor(s2, off); }
    float mean = s / F;
    float var  = s2 / F - mean * mean;
    float inv  = 1.f / sqrtf(var + 1e-5f);
    u16x4* o4 = reinterpret_cast<u16x4*>(out + (size_t)row * F);
    for (int j = lane; j < F4; j += 64) {
        float4 v = r4[j], gm = g4[j], bt = b4[j];
        u16x4 o;
        o[0] = f2bf((v.x - mean) * inv * gm.x + bt.x);
        o[1] = f2bf((v.y - mean) * inv * gm.y + bt.y);
        o[2] = f2bf((v.z - mean) * inv * gm.z + bt.z);
        o[3] = f2bf((v.w - mean) * inv * gm.w + bt.w);
        o4[j] = o;
    }
}

// ------- bf16 MFMA GEMM (templated tile): C[M,N] = A[M,K] @ Bt[N,K]^T ---------
template <int BM, int BN>
__global__ __launch_bounds__(256)
void gemm_bt(const u16* __restrict__ A, const u16* __restrict__ Bt,
             const float* __restrict__ bias, const float* __restrict__ res,
             float* __restrict__ out32, u16* __restrict__ out16,
             int M, int N, int K) {
    constexpr int WM = BM / 2, WN = BN / 2, FM = WM / 16, FN = WN / 16;
    __shared__ __align__(16) u16 As[BM * 32];
    __shared__ __align__(16) u16 Bs[BN * 32];
    const int tid = threadIdx.x;
    const int lane = tid & 63;
    const int wid = tid >> 6;
    const int wr = wid >> 1, wc = wid & 1;
    const int m0 = blockIdx.y * BM, n0 = blockIdx.x * BN;
    const int r16 = lane & 15;
    const int g8  = (lane >> 4) * 8;
    const int w16 = wid * 16;
    const int ln4 = lane >> 2;
    const int cb8 = (lane & 3) * 8;

    const f32x4 zero4 = {0.f, 0.f, 0.f, 0.f};
    f32x4 acc[FM][FN];
#pragma unroll
    for (int m = 0; m < FM; ++m)
#pragma unroll
        for (int n = 0; n < FN; ++n) acc[m][n] = zero4;

    for (int k0 = 0; k0 < K; k0 += 32) {
#pragma unroll
        for (int p = 0; p < BM / 64; ++p) {
            const int rb = p * 64 + w16;
            gload_lds16(A + (size_t)(m0 + rb + ln4) * K + k0 + cb8, &As[rb * 32]);
        }
#pragma unroll
        for (int p = 0; p < BN / 64; ++p) {
            const int rb = p * 64 + w16;
            gload_lds16(Bt + (size_t)(n0 + rb + ln4) * K + k0 + cb8, &Bs[rb * 32]);
        }
        __syncthreads();
        short8 af[FM], bfr[FN];
#pragma unroll
        for (int m = 0; m < FM; ++m)
            af[m] = *reinterpret_cast<const short8*>(&As[(wr * WM + m * 16 + r16) * 32 + g8]);
#pragma unroll
        for (int n = 0; n < FN; ++n)
            bfr[n] = *reinterpret_cast<const short8*>(&Bs[(wc * WN + n * 16 + r16) * 32 + g8]);
#pragma unroll
        for (int m = 0; m < FM; ++m)
#pragma unroll
            for (int n = 0; n < FN; ++n)
                acc[m][n] = __builtin_amdgcn_mfma_f32_16x16x32_bf16(af[m], bfr[n], acc[m][n], 0, 0, 0);
        __syncthreads();
    }

    const int rg = (lane >> 4) * 4;
#pragma unroll
    for (int m = 0; m < FM; ++m) {
#pragma unroll
        for (int n = 0; n < FN; ++n) {
#pragma unroll
            for (int j = 0; j < 4; ++j) {
                int row = m0 + wr * WM + m * 16 + rg + j;
                int col = n0 + wc * WN + n * 16 + r16;
                float v = acc[m][n][j];
                if (bias) v += bias[col];
                size_t off = (size_t)row * N + col;
                if (res) v += res[off];
                if (out32) out32[off] = v;
                if (out16) out16[off] = f2bf(v);
            }
        }
    }
}

// ---- GEGLU-fused GEMM: out[M,Nh] = (A@Wa^T + ba) * gelu(A@Wg^T + bg) ---------
// Bt rows [0,Nh) = a-weights, rows [Nh,2Nh) = g-weights. Block: BM x 64 out cols.
template <int BM>
__global__ __launch_bounds__(256)
void gemm_geglu(const u16* __restrict__ A, const u16* __restrict__ Bt,
                const float* __restrict__ bias, u16* __restrict__ out16,
                int M, int Nh, int K) {
    constexpr int WM = BM / 2, FM = WM / 16;
    __shared__ __align__(16) u16 As[BM * 32];
    __shared__ __align__(16) u16 Bs[128 * 32];
    const int tid = threadIdx.x;
    const int lane = tid & 63;
    const int wid = tid >> 6;
    const int wr = wid >> 1, wc = wid & 1;
    const int m0 = blockIdx.y * BM, n0 = blockIdx.x * 64;
    const int r16 = lane & 15;
    const int g8  = (lane >> 4) * 8;
    const int w16 = wid * 16;
    const int ln4 = lane >> 2;
    const int cb8 = (lane & 3) * 8;

    const f32x4 zero4 = {0.f, 0.f, 0.f, 0.f};
    f32x4 acc_a[FM][2], acc_g[FM][2];
#pragma unroll
    for (int m = 0; m < FM; ++m)
#pragma unroll
        for (int n = 0; n < 2; ++n) { acc_a[m][n] = zero4; acc_g[m][n] = zero4; }

    for (int k0 = 0; k0 < K; k0 += 32) {
#pragma unroll
        for (int p = 0; p < BM / 64; ++p) {
            const int rb = p * 64 + w16;
            gload_lds16(A + (size_t)(m0 + rb + ln4) * K + k0 + cb8, &As[rb * 32]);
        }
        // B: rows 0..63 = a-half (Bt row n0+r), rows 64..127 = g-half (Bt row Nh+n0+r)
        gload_lds16(Bt + (size_t)(n0 + w16 + ln4) * K + k0 + cb8, &Bs[w16 * 32]);
        gload_lds16(Bt + (size_t)(Nh + n0 + w16 + ln4) * K + k0 + cb8, &Bs[(64 + w16) * 32]);
        __syncthreads();
        short8 af[FM], ba[2], bg[2];
#pragma unroll
        for (int m = 0; m < FM; ++m)
            af[m] = *reinterpret_cast<const short8*>(&As[(wr * WM + m * 16 + r16) * 32 + g8]);
#pragma unroll
        for (int n = 0; n < 2; ++n) {
            ba[n] = *reinterpret_cast<const short8*>(&Bs[(wc * 32 + n * 16 + r16) * 32 + g8]);
            bg[n] = *reinterpret_cast<const short8*>(&Bs[(64 + wc * 32 + n * 16 + r16) * 32 + g8]);
        }
#pragma unroll
        for (int m = 0; m < FM; ++m)
#pragma unroll
            for (int n = 0; n < 2; ++n) {
                acc_a[m][n] = __builtin_amdgcn_mfma_f32_16x16x32_bf16(af[m], ba[n], acc_a[m][n], 0, 0, 0);
                acc_g[m][n] = __builtin_amdgcn_mfma_f32_16x16x32_bf16(af[m], bg[n], acc_g[m][n], 0, 0, 0);
            }
        __syncthreads();
    }

    const int rg = (lane >> 4) * 4;
#pragma unroll
    for (int m = 0; m < FM; ++m) {
#pragma unroll
        for (int n = 0; n < 2; ++n) {
#pragma unroll
            for (int j = 0; j < 4; ++j) {
                int row = m0 + wr * WM + m * 16 + rg + j;
                int col = n0 + wc * 32 + n * 16 + r16;
                float a = acc_a[m][n][j] + bias[col];
                float g = acc_g[m][n][j] + bias[Nh + col];
                out16[(size_t)row * Nh + col] = f2bf(a * gelu_exact(g));
            }
        }
    }
}

// ---------------- MFMA SDPA attention, 256 keys, 8 heads, dh=64 ----------------
__global__ __launch_bounds__(256)
void k_attn_mfma(const u16* __restrict__ Qb, int sq, const u16* __restrict__ Kb,
                 int sk, const u16* __restrict__ VT, u16* __restrict__ out, int NQ) {
    __shared__ float sc[16][268];
    __shared__ u16   pb[16][268];
    const int tid = threadIdx.x, lane = tid & 63, w = tid >> 6;
    const int nqb = NQ >> 4;
    const int q0 = (blockIdx.x % nqb) << 4;
    const int h = (blockIdx.x / nqb) & 7;
    const int b = blockIdx.x / (nqb * 8);
    const int r16 = lane & 15, g8 = (lane >> 4) * 8, rq = (lane >> 4) * 4;

    const size_t qrow = ((size_t)(b * NQ + q0 + r16)) * sq + h * 64;
    const short8 af0 = *reinterpret_cast<const short8*>(Qb + qrow + g8);
    const short8 af1 = *reinterpret_cast<const short8*>(Qb + qrow + 32 + g8);
    const u16* kb = Kb + (size_t)b * 256 * sk + h * 64;
    const f32x4 zero4 = {0.f, 0.f, 0.f, 0.f};
#pragma unroll
    for (int t = 0; t < 4; ++t) {
        const size_t krow = (size_t)(t * 64 + w * 16 + r16) * sk;
        const short8 bf0 = *reinterpret_cast<const short8*>(kb + krow + g8);
        const short8 bf1 = *reinterpret_cast<const short8*>(kb + krow + 32 + g8);
        f32x4 acc = __builtin_amdgcn_mfma_f32_16x16x32_bf16(af0, bf0, zero4, 0, 0, 0);
        acc = __builtin_amdgcn_mfma_f32_16x16x32_bf16(af1, bf1, acc, 0, 0, 0);
        const int col = t * 64 + w * 16 + r16;
#pragma unroll
        for (int j = 0; j < 4; ++j) sc[rq + j][col] = acc[j] * 0.125f;
    }
    __syncthreads();
#pragma unroll
    for (int qi = 0; qi < 4; ++qi) {
        const int q = w * 4 + qi;
        float4 v = *reinterpret_cast<const float4*>(&sc[q][lane * 4]);
        float m = fmaxf(fmaxf(v.x, v.y), fmaxf(v.z, v.w));
#pragma unroll
        for (int off = 32; off; off >>= 1) m = fmaxf(m, __shfl_xor(m, off));
        float e0 = expf(v.x - m), e1 = expf(v.y - m), e2 = expf(v.z - m), e3 = expf(v.w - m);
        float sum = e0 + e1 + e2 + e3;
#pragma unroll
        for (int off = 32; off; off >>= 1) sum += __shfl_xor(sum, off);
        float inv = 1.f / sum;
        u16x4 p4;
        p4[0] = f2bf(e0 * inv); p4[1] = f2bf(e1 * inv);
        p4[2] = f2bf(e2 * inv); p4[3] = f2bf(e3 * inv);
        *reinterpret_cast<u16x4*>(&pb[q][lane * 4]) = p4;
    }
    __syncthreads();
    f32x4 o = zero4;
    const u16* vt = VT + ((size_t)(b * 512 + h * 64 + w * 16 + r16)) * 256;
#pragma unroll
    for (int kk = 0; kk < 8; ++kk) {
        const short8 pa = *reinterpret_cast<const short8*>(&pb[r16][kk * 32 + g8]);
        const short8 vv = *reinterpret_cast<const short8*>(vt + kk * 32 + g8);
        o = __builtin_amdgcn_mfma_f32_16x16x32_bf16(pa, vv, o, 0, 0, 0);
    }
#pragma unroll
    for (int j = 0; j < 4; ++j)
        out[((size_t)(b * NQ + q0 + rq + j)) * 512 + h * 64 + w * 16 + r16] = f2bf(o[j]);
}

// ---------------- top-32 sparse self-attention, N=2304, dh=64 ------------------
// 8 queries/block; XCD-swizzled so all blocks of one (b,h) share an XCD L2.
// Q,K,V packed bf16 rows of stride 1536 (col offsets 0/512/1024).
__global__ __launch_bounds__(256)
void k_topk_attn(const u16* __restrict__ Qb, const u16* __restrict__ Kb,
                 const u16* __restrict__ Vb, u16* __restrict__ out) {
    __shared__ u16   sc[8][2312];
    __shared__ int   ilist[8][32];
    __shared__ float wlist[8][32];
    const int tid = threadIdx.x, lane = tid & 63, w = tid >> 6;
    // swizzle decode: h = phys&7 pins all 288 blocks of (b,h) to one XCD slot
    const int h = blockIdx.x & 7;
    const int t7 = blockIdx.x >> 3;
    const int b = t7 / 288;
    const int q0 = (t7 % 288) * 8;
    const int r16 = lane & 15;
    const int g8  = (lane >> 4) * 8;
    const int rq  = (lane >> 4) * 4;

    const size_t qrow = ((size_t)(b * 2304 + q0 + r16)) * 1536 + h * 64;
    const short8 af0 = *reinterpret_cast<const short8*>(Qb + qrow + g8);
    const short8 af1 = *reinterpret_cast<const short8*>(Qb + qrow + 32 + g8);

    const u16* kb = Kb + (size_t)b * 2304 * 1536 + h * 64;
    const f32x4 zero4 = {0.f, 0.f, 0.f, 0.f};
    // score phase, 2-deep prefetch (4 loads in flight)
    const size_t kr0 = (size_t)(w * 16 + r16) * 1536;
    const size_t kr1 = (size_t)(64 + w * 16 + r16) * 1536;
    short8 a0 = *reinterpret_cast<const short8*>(kb + kr0 + g8);
    short8 a1 = *reinterpret_cast<const short8*>(kb + kr0 + 32 + g8);
    short8 b0 = *reinterpret_cast<const short8*>(kb + kr1 + g8);
    short8 b1 = *reinterpret_cast<const short8*>(kb + kr1 + 32 + g8);
    for (int t = 0; t < 36; ++t) {
        const int tn = (t < 34) ? t + 2 : t;
        const size_t krn = (size_t)(tn * 64 + w * 16 + r16) * 1536;
        const short8 n0 = *reinterpret_cast<const short8*>(kb + krn + g8);
        const short8 n1 = *reinterpret_cast<const short8*>(kb + krn + 32 + g8);
        f32x4 acc = __builtin_amdgcn_mfma_f32_16x16x32_bf16(af0, a0, zero4, 0, 0, 0);
        acc = __builtin_amdgcn_mfma_f32_16x16x32_bf16(af1, a1, acc, 0, 0, 0);
        const int col = t * 64 + w * 16 + r16;
        if (rq < 8) {
#pragma unroll
            for (int j = 0; j < 4; ++j)
                sc[rq + j][col] = __half_as_ushort(__float2half(acc[j] * 0.125f));
        }
        a0 = b0; a1 = b1; b0 = n0; b1 = n1;
    }
    __syncthreads();

    const ull ltm = (1ull << lane) - 1ull;
    for (int round = 0; round < 2; ++round) {
        const int q = w * 2 + round;
        unsigned key[36];
        unsigned kmax = 0;
#pragma unroll
        for (int j = 0; j < 36; ++j) {
            unsigned hb = sc[q][lane + j * 64];
            key[j] = h2key(hb);
            kmax = key[j] > kmax ? key[j] : kmax;
        }
#pragma unroll
        for (int off = 32; off; off >>= 1) {
            unsigned o = (unsigned)__shfl_xor((int)kmax, off);
            kmax = o > kmax ? o : kmax;
        }
        // exact 32nd-largest key: MSB binary search, ballot counting
        unsigned thr = 0;
        for (int bit = 15; bit >= 0; --bit) {
            unsigned cand = thr | (1u << bit);
            int c = 0;
#pragma unroll
            for (int j = 0; j < 36; ++j)
                c += (int)__popcll(__ballot(key[j] >= cand));
            if (c >= 32) { thr = cand; if (c == 32) break; }
        }
        // strict pass: keys > thr
        int tot = 0;
#pragma unroll
        for (int j = 0; j < 36; ++j) {
            bool p = key[j] > thr;
            ull m = __ballot(p);
            if (p) {
                int pos = tot + (int)__popcll(m & ltm);
                ilist[q][pos] = j * 64 + lane;
                wlist[q][pos] = key2f(key[j]);
            }
            tot += (int)__popcll(m);
        }
        // tie pass: keys == thr in ascending index order
        const int r = 32 - tot;
        const float tv = key2f(thr);
        int t2 = 0;
#pragma unroll
        for (int j = 0; j < 36; ++j) {
            bool p = (key[j] == thr) && (t2 < 32);
            ull m = __ballot(p);
            if (p) {
                int pos = t2 + (int)__popcll(m & ltm);
                if (pos < r) {
                    ilist[q][tot + pos] = j * 64 + lane;
                    wlist[q][tot + pos] = tv;
                }
            }
            t2 += (int)__popcll(m);
        }
        const float mf = key2f(kmax);
        float e = 0.f;
        if (lane < 32) e = expf(wlist[q][lane] - mf);
        float sum = e;
#pragma unroll
        for (int off = 32; off; off >>= 1) sum += __shfl_xor(sum, off);
        if (lane < 32) wlist[q][lane] = e / sum;
        // PV gather: batch all 32 row loads, then reduce
        const u16* vb = Vb + (size_t)b * 2304 * 1536 + h * 64 + lane;
        u16 vr[32];
#pragma unroll
        for (int i = 0; i < 32; ++i)
            vr[i] = vb[(size_t)ilist[q][i] * 1536];
        float o = 0.f;
#pragma unroll
        for (int i = 0; i < 32; ++i)
            o += wlist[q][i] * bf2f(vr[i]);
        out[((size_t)(b * 2304 + q0 + q)) * 512 + h * 64 + lane] = f2bf(o);
    }
}

// ---------------- workspace layout (bytes) ---------------
static constexpr size_t O_WQKVC = 0;                       // [1536,768]
static constexpr size_t O_WOC   = O_WQKVC + 2359296;       // [768,512]
static constexpr size_t O_W1C   = O_WOC + 786432;          // [6144,768]
static constexpr size_t O_W2C   = O_W1C + 9437184;         // [768,3072]
static constexpr size_t O_WQKVI = O_W2C + 4718592;         // [1536,512]
static constexpr size_t O_WOI   = O_WQKVI + 1572864;       // [512,512]
static constexpr size_t O_WQX   = O_WOI + 524288;          // [512,512]
static constexpr size_t O_WKVX  = O_WQX + 524288;          // [1024,768]
static constexpr size_t O_WOX   = O_WKVX + 1572864;        // [512,512]
static constexpr size_t O_W1I   = O_WOX + 524288;          // [4096,512]
static constexpr size_t O_W2I   = O_W1I + 4194304;         // [512,2048]
static constexpr size_t O_CF16  = O_W2I + 2097152;         // [512,768] bf16
static constexpr size_t O_H     = O_CF16 + 786432;         // [4608,512] f32
static constexpr size_t O_H2    = O_H + 9437184;           // [4608,512] f32
static constexpr size_t O_S     = O_H2 + 9437184;
// ctx phase
static constexpr size_t O_CN16  = O_S;                     // [512,768] bf16
static constexpr size_t O_QKVC  = O_CN16 + 786432;         // [512,1536] bf16
static constexpr size_t O_VTC   = O_QKVC + 1572864;        // [2,512,256] bf16
static constexpr size_t O_AO16  = O_VTC + 524288;          // [512,512] bf16
static constexpr size_t O_CBUF  = O_AO16 + 524288;         // [512,768] f32
static constexpr size_t O_C16   = O_CBUF + 1572864;        // [512,768] bf16
static constexpr size_t O_AG16  = O_C16 + 786432;          // [512,3072] bf16
// img phase 1
static constexpr size_t O_XLN   = O_S;                     // [4608,512] bf16
static constexpr size_t O_QKVI  = O_XLN + 4718592;         // [4608,1536] bf16
static constexpr size_t O_TO16  = O_QKVI + 14155776;       // [4608,512] bf16
// img phase 2
static constexpr size_t O_H2LN  = O_S;                     // [4608,512] bf16
static constexpr size_t O_XQ    = O_H2LN + 4718592;        // [4608,512] bf16
static constexpr size_t O_KVX   = O_XQ + 4718592;          // [512,1024] bf16
static constexpr size_t O_VTX   = O_KVX + 1048576;         // [2,512,256] bf16
static constexpr size_t O_XO16  = O_VTX + 524288;          // [4608,512] bf16
// ff phase
static constexpr size_t O_H3    = O_S;                     // [4608,512] bf16
static constexpr size_t O_AGI   = O_H3 + 4718592;          // [4608,2048] bf16

extern "C" void kernel_launch(void* const* d_in, const int* in_sizes, int n_in,
                              void* d_out, int out_size, void* d_ws, size_t ws_size,
                              hipStream_t stream) {
    (void)in_sizes; (void)n_in; (void)out_size; (void)ws_size;
    const float* x      = (const float*)d_in[0];
    const float* ctx    = (const float*)d_in[1];
    const float* ctx_wq = (const float*)d_in[3];
    const float* ctx_wk = (const float*)d_in[4];
    const float* ctx_wv = (const float*)d_in[5];
    const float* ctx_wo = (const float*)d_in[6];
    const float* ctx_bo = (const float*)d_in[7];
    const float* cn_g   = (const float*)d_in[8];
    const float* cn_b   = (const float*)d_in[9];
    const float* im_wq  = (const float*)d_in[10];
    const float* im_wk  = (const float*)d_in[11];
    const float* im_wv  = (const float*)d_in[12];
    const float* im_wo  = (const float*)d_in[13];
    const float* im_bo  = (const float*)d_in[14];
    const float* xc_wq  = (const float*)d_in[15];
    const float* xc_wk  = (const float*)d_in[16];
    const float* xc_wv  = (const float*)d_in[17];
    const float* xc_wo  = (const float*)d_in[18];
    const float* xc_bo  = (const float*)d_in[19];
    const float* ffc_w1 = (const float*)d_in[20];
    const float* ffc_b1 = (const float*)d_in[21];
    const float* ffc_w2 = (const float*)d_in[22];
    const float* ffc_b2 = (const float*)d_in[23];
    const float* ffi_w1 = (const float*)d_in[24];
    const float* ffi_b1 = (const float*)d_in[25];
    const float* ffi_w2 = (const float*)d_in[26];
    const float* ffi_b2 = (const float*)d_in[27];
    const float* n1_g   = (const float*)d_in[28];
    const float* n1_b   = (const float*)d_in[29];
    const float* n2_g   = (const float*)d_in[30];
    const float* n2_b   = (const float*)d_in[31];
    const float* n3_g   = (const float*)d_in[32];
    const float* n3_b   = (const float*)d_in[33];
    char* ws = (char*)d_ws;
    float* out = (float*)d_out;
    auto Wp = [&](size_t off) { return (u16*)(ws + off); };
    auto Fp = [&](size_t off) { return (float*)(ws + off); };
    dim3 tb(32, 8);

    // ---- one batched weight transpose+cast (QKV fused along N) ----
    TBatch tbat;
    const float* srcs[16] = {ctx_wq, ctx_wk, ctx_wv, ctx_wo, ffc_w1, ffc_w2,
                             im_wq, im_wk, im_wv, im_wo, xc_wq, xc_wk, xc_wv,
                             xc_wo, ffi_w1, ffi_w2};
    const size_t dsts[16] = {O_WQKVC, O_WQKVC + 786432, O_WQKVC + 1572864, O_WOC,
                             O_W1C, O_W2C,
                             O_WQKVI, O_WQKVI + 524288, O_WQKVI + 1048576, O_WOI,
                             O_WQX, O_WKVX, O_WKVX + 786432, O_WOX,
                             O_W1I, O_W2I};
    const int Ks[16] = {768, 768, 768, 512, 768, 3072, 512, 512, 512, 512,
                        512, 768, 768, 512, 512, 2048};
    const int Ns[16] = {512, 512, 512, 768, 6144, 768, 512, 512, 512, 512,
                        512, 512, 512, 512, 4096, 512};
    int acc = 0;
    for (int i = 0; i < 16; ++i) {
        tbat.src[i] = srcs[i];
        tbat.dst[i] = Wp(dsts[i]);
        tbat.K[i] = Ks[i];
        tbat.N[i] = Ns[i];
        tbat.start[i] = acc;
        acc += (Ns[i] >> 5) * (Ks[i] >> 5);
    }
    tbat.start[16] = acc;
    k_transpose_cast_batch<<<acc, tb, 0, stream>>>(tbat);

    // ---- context path ----
    k_ln_bf16<<<128, 256, 0, stream>>>(ctx, cn_g, cn_b, Wp(O_CN16), 768);
    gemm_bt<64, 64><<<dim3(24, 8), 256, 0, stream>>>(Wp(O_CN16), Wp(O_WQKVC), nullptr, nullptr, nullptr, Wp(O_QKVC), 512, 1536, 768);
    k_vtrans16<<<dim3(16, 8, 2), tb, 0, stream>>>(Wp(O_QKVC), 1536, 1024, Wp(O_VTC));
    k_attn_mfma<<<256, 256, 0, stream>>>(Wp(O_QKVC), 1536, Wp(O_QKVC) + 512, 1536, Wp(O_VTC), Wp(O_AO16), 256);
    gemm_bt<64, 64><<<dim3(12, 8), 256, 0, stream>>>(Wp(O_AO16), Wp(O_WOC), ctx_bo, ctx, Fp(O_CBUF), Wp(O_C16), 512, 768, 512);
    gemm_geglu<128><<<dim3(48, 4), 256, 0, stream>>>(Wp(O_C16), Wp(O_W1C), ffc_b1, Wp(O_AG16), 512, 3072, 768);
    gemm_bt<64, 64><<<dim3(12, 8), 256, 0, stream>>>(Wp(O_AG16), Wp(O_W2C), ffc_b2, Fp(O_CBUF), nullptr, Wp(O_CF16), 512, 768, 3072);

    // ---- image: top-k self-attention ----
    k_ln_bf16<<<1152, 256, 0, stream>>>(x, n1_g, n1_b, Wp(O_XLN), 512);
    gemm_bt<128, 128><<<dim3(12, 36), 256, 0, stream>>>(Wp(O_XLN), Wp(O_WQKVI), nullptr, nullptr, nullptr, Wp(O_QKVI), 4608, 1536, 512);
    k_topk_attn<<<4608, 256, 0, stream>>>(Wp(O_QKVI), Wp(O_QKVI) + 512, Wp(O_QKVI) + 1024, Wp(O_TO16));
    gemm_bt<128, 64><<<dim3(8, 36), 256, 0, stream>>>(Wp(O_TO16), Wp(O_WOI), im_bo, x, Fp(O_H), nullptr, 4608, 512, 512);

    // ---- image -> context cross-attention ----
    k_ln_bf16<<<1152, 256, 0, stream>>>(Fp(O_H), n2_g, n2_b, Wp(O_H2LN), 512);
    gemm_bt<128, 64><<<dim3(8, 36), 256, 0, stream>>>(Wp(O_H2LN), Wp(O_WQX), nullptr, nullptr, nullptr, Wp(O_XQ), 4608, 512, 512);
    gemm_bt<64, 64><<<dim3(16, 8), 256, 0, stream>>>(Wp(O_CF16), Wp(O_WKVX), nullptr, nullptr, nullptr, Wp(O_KVX), 512, 1024, 768);
    k_vtrans16<<<dim3(16, 8, 2), tb, 0, stream>>>(Wp(O_KVX), 1024, 512, Wp(O_VTX));
    k_attn_mfma<<<2304, 256, 0, stream>>>(Wp(O_XQ), 512, Wp(O_KVX), 1024, Wp(O_VTX), Wp(O_XO16), 2304);
    gemm_bt<128, 64><<<dim3(8, 36), 256, 0, stream>>>(Wp(O_XO16), Wp(O_WOX), xc_bo, Fp(O_H), Fp(O_H2), nullptr, 4608, 512, 512);

    // ---- image GEGLU FF ----
    k_ln_bf16<<<1152, 256, 0, stream>>>(Fp(O_H2), n3_g, n3_b, Wp(O_H3), 512);
    gemm_geglu<128><<<dim3(32, 36), 256, 0, stream>>>(Wp(O_H3), Wp(O_W1I), ffi_b1, Wp(O_AGI), 4608, 2048, 512);
    gemm_bt<128, 64><<<dim3(8, 36), 256, 0, stream>>>(Wp(O_AGI), Wp(O_W2I), ffi_b2, Fp(O_H2), out, nullptr, 4608, 512, 2048);
}